// Round 14
// baseline (165.334 us; speedup 1.0000x reference)
//
#include <hip/hip_runtime.h>

#define BB 4
#define LL 4096
#define DD 256
#define MAXOFF 80    // max per-batch partial slots (exact bound: 78), slot = 256q x 256d

typedef short bf16x8 __attribute__((ext_vector_type(8)));
typedef short bf16x4 __attribute__((ext_vector_type(4)));
typedef float f32x4 __attribute__((ext_vector_type(4)));
typedef unsigned u32x4 __attribute__((ext_vector_type(4)));
typedef unsigned short u16;

__device__ inline u16 f2b(float f) {
    union { float f; unsigned u; } v; v.f = f;
    unsigned r = (v.u + 0x7fffu + ((v.u >> 16) & 1u)) >> 16;  // RNE
    return (u16)r;
}
__device__ inline float b2f(short s) {
    union { unsigned u; float f; } v; v.u = ((unsigned)(unsigned short)s) << 16;
    return v.f;
}
// pack 2 fp32 -> 2 bf16 (TRUNCATE) in one v_perm_b32
__device__ inline unsigned pk2(float lo, float hi) {
    union { float f; unsigned u; } a, b; a.f = lo; b.f = hi;
    return __builtin_amdgcn_perm(b.u, a.u, 0x07060302u);
}

__device__ inline f32x4 mfma32(bf16x8 a, bf16x8 b, f32x4 c) {
    return __builtin_amdgcn_mfma_f32_16x16x32_bf16(a, b, c, 0, 0, 0);
}
__device__ inline f32x4 mfma16(bf16x4 a, bf16x4 b, f32x4 c) {
    return __builtin_amdgcn_mfma_f32_16x16x16bf16_1k(a, b, c, 0, 0, 0);
}

__device__ inline void gl_lds(const u16* g, u16* l) {
    __builtin_amdgcn_global_load_lds(
        (const __attribute__((address_space(1))) void*)g,
        (__attribute__((address_space(3))) void*)l, 16, 0, 0);
}

// ===========================================================================
// Round 26: qkv TLP attack (single variable vs the 152.9us session best).
// Evidence: total-attn is ~111us every round; qkv re-grid (4->2 blk/CU)
// added +11us TWICE -> qkv is a sizeable latency-bound kernel that responds
// to occupancy. This round splits Q/K/V into separate blocks: 3072 blocks,
// same per-wave geometry as round-2 (32 tok x 128 dims, 256 thr), ONE matrix
// per block (32 MFMA/wave, acc 16 VGPR, 10.2KB LDS) -> __launch_bounds__
// (256,5) gives 5 blk/CU = 20 waves/CU (was 16) with VGPR cap 102 (~85 est).
// attn/oproj/wconv byte-identical to the session-best source.
// ===========================================================================

__global__ __launch_bounds__(256) void wconv_kernel(
    const float* __restrict__ Wq, const float* __restrict__ Wk,
    const float* __restrict__ Wv, const float* __restrict__ Wo,
    u16* __restrict__ wf, u16* __restrict__ wo16)
{
    const int w = threadIdx.x >> 6, lane = threadIdx.x & 63;
    const int q4 = lane >> 4, ln = lane & 15;
    const int id = blockIdx.x * 4 + w;          // 0..511
    const int mat = id >> 7, rem = id & 127, ct = rem >> 3, ks = rem & 7;
    if (mat < 3) {
        const float* W = (mat == 0) ? Wq : (mat == 1) ? Wk : Wv;
        const float* src = W + (size_t)(ct * 16 + ln) * DD + ks * 32 + q4 * 8;
        float4 f0 = ((const float4*)src)[0], f1 = ((const float4*)src)[1];
        bf16x8 t;
        t[0] = (short)f2b(f0.x); t[1] = (short)f2b(f0.y);
        t[2] = (short)f2b(f0.z); t[3] = (short)f2b(f0.w);
        t[4] = (short)f2b(f1.x); t[5] = (short)f2b(f1.y);
        t[6] = (short)f2b(f1.z); t[7] = (short)f2b(f1.w);
        *(bf16x8*)(wf + (size_t)mat * 65536 + (ct * 8 + ks) * 512 + lane * 8) = t;
    } else {
        const float* src = Wo + (size_t)(ct * 16 + ln) * DD + ks * 32 + q4 * 4;
        float4 f0 = *(const float4*)src;
        float4 f1 = *(const float4*)(src + 16);
        bf16x4 t0, t1;
        t0[0] = (short)f2b(f0.x); t0[1] = (short)f2b(f0.y);
        t0[2] = (short)f2b(f0.z); t0[3] = (short)f2b(f0.w);
        t1[0] = (short)f2b(f1.x); t1[1] = (short)f2b(f1.y);
        t1[2] = (short)f2b(f1.z); t1[3] = (short)f2b(f1.w);
        *(bf16x4*)(wo16 + (size_t)(ct * 16 + 2 * ks) * 256 + lane * 4) = t0;
        *(bf16x4*)(wo16 + (size_t)(ct * 16 + 2 * ks + 1) * 256 + lane * 4) = t1;
    }
}

// ---------------------------------------------------------------------------
// Kernel 1: QKV projection, split per matrix. 3072 blocks x 256 thr, 5/CU.
// bid = mat*1024 + tg*2 + half; per-block: 32 tokens x 128 dims of ONE matrix.
// Per-wave code identical to round-2 (tl = w&1, dq = w>>1, 8 ks x 4 cl MFMA,
// identical LDS epilogues and frag-order store formulas).
// ---------------------------------------------------------------------------
__global__ __launch_bounds__(256, 5) void qkv_kernel(
    const float* __restrict__ x, const u16* __restrict__ wf,
    u16* __restrict__ qf, u16* __restrict__ kf_, u16* __restrict__ vf_)
{
    __shared__ u16 lds[128 * 40];   // 10.2 KB; Q/K use first 32*136 = 8.7 KB

    const int w = threadIdx.x >> 6, lane = threadIdx.x & 63;
    const int q4 = lane >> 4, ln = lane & 15;
    const int bid = blockIdx.x;                 // 0..3071
    const int mat = bid >> 10;                  // 0=Q, 1=K, 2=V
    const int rem = bid & 1023;
    const int tg = rem >> 1, half = rem & 1;
    const int tl = w & 1, dq = w >> 1;

    // A-frags: 16 token rows (fp32 -> bf16)
    bf16x8 a[8];
    {
        const float* xrow = x + (size_t)(tg * 32 + tl * 16 + ln) * DD;
        #pragma unroll
        for (int ks = 0; ks < 8; ++ks) {
            const float4* p = (const float4*)(xrow + ks * 32 + q4 * 8);
            float4 f0 = p[0], f1 = p[1];
            bf16x8 t;
            t[0] = (short)f2b(f0.x); t[1] = (short)f2b(f0.y);
            t[2] = (short)f2b(f0.z); t[3] = (short)f2b(f0.w);
            t[4] = (short)f2b(f1.x); t[5] = (short)f2b(f1.y);
            t[6] = (short)f2b(f1.z); t[7] = (short)f2b(f1.w);
            a[ks] = t;
        }
    }

    const u16* wb = wf + (size_t)mat * 65536;
    f32x4 acc[4];
    #pragma unroll
    for (int cl = 0; cl < 4; ++cl) acc[cl] = f32x4{0.f, 0.f, 0.f, 0.f};

    #pragma unroll
    for (int ks = 0; ks < 8; ++ks) {
        #pragma unroll
        for (int cl = 0; cl < 4; ++cl) {
            const int ct = half * 8 + dq * 4 + cl;
            bf16x8 b0 = *(const bf16x8*)(wb + ((size_t)ct * 8 + ks) * 512 + lane * 8);
            acc[cl] = mfma32(a[ks], b0, acc[cl]);
        }
    }

    if (mat < 2) {
        // Q/K: row-major epilogue [tok 32][dim_local 128 +pad(136)]
        #pragma unroll
        for (int cl = 0; cl < 4; ++cl) {
            const int coll = (dq * 4 + cl) * 16 + ln;   // local dim [0,128)
            #pragma unroll
            for (int r = 0; r < 4; ++r) {
                const int tok = tl * 16 + q4 * 4 + r;   // local token [0,32)
                lds[tok * 136 + coll] = f2b(acc[cl][r]);
            }
        }
        __syncthreads();
        u16* dstbuf = (mat == 0) ? qf : kf_;
        const int h = w & 1;
        #pragma unroll
        for (int e = 0; e < 2; ++e) {
            const int ksl = 2 * dq + e;                 // local K-chunk [0,4)
            const int ks = half * 4 + ksl;              // global K-chunk [0,8)
            bf16x8 aq = *(const bf16x8*)&lds[(h * 16 + ln) * 136 + ksl * 32 + q4 * 8];
            *(bf16x8*)(dstbuf + (size_t)((tg * 2 + h) * 8 + ks) * 512 + lane * 8) = aq;
        }
    } else {
        // V: transposed epilogue [dim_local 128][tok 32 +pad(40)]
        #pragma unroll
        for (int cl = 0; cl < 4; ++cl) {
            const int coll = (dq * 4 + cl) * 16 + ln;   // local dim [0,128)
            #pragma unroll
            for (int r = 0; r < 4; ++r) {
                const int tok = tl * 16 + q4 * 4 + r;   // local token [0,32)
                lds[coll * 40 + tok] = f2b(acc[cl][r]);
            }
        }
        __syncthreads();
        #pragma unroll
        for (int e = 0; e < 2; ++e) {
            const int dt_l = 2 * w + e;                 // local d-tile [0,8)
            bf16x4 lo = *(const bf16x4*)&lds[(dt_l * 16 + ln) * 40 + q4 * 4];
            bf16x4 hi = *(const bf16x4*)&lds[(dt_l * 16 + ln) * 40 + 16 + q4 * 4];
            bf16x8 t;
            t[0] = lo[0]; t[1] = lo[1]; t[2] = lo[2]; t[3] = lo[3];
            t[4] = hi[0]; t[5] = hi[1]; t[6] = hi[2]; t[7] = hi[3];
            *(bf16x8*)(vf_ + (size_t)(tg * 16 + half * 8 + dt_l) * 512 + lane * 8) = t;
        }
    }
}

// ---------------------------------------------------------------------------
// Kernel 2: causal ReLU attention (session-best, unchanged). 256-query
// groups, 8 waves x 32 queries, 256 blocks x 512 threads, 64KB LDS dbuf.
// ---------------------------------------------------------------------------
__global__ __launch_bounds__(512, 2) void attn_kernel(
    const u16* __restrict__ qf, const u16* __restrict__ kfr,
    const u16* __restrict__ vfr, u16* __restrict__ part)
{
    __shared__ u16 buf[2][32][512];   // 64 KB: K (chunks 0-15) + V (16-31), dbuf

    const int id = blockIdx.x;                  // 0..255
    const int xcd = id & 7;
    const int b = xcd >> 1;                     // 2 XCDs per batch
    const int j = ((xcd & 1) << 5) | (id >> 3); // segment 0..63

    const int w = threadIdx.x >> 6, lane = threadIdx.x & 63;
    const int q4 = lane >> 4, ln = lane & 15;

    const int u0 = 17 * j;
    const int u1 = u0 + 17;

    int g = (int)((sqrtf((float)u0 + 1.0f) - 1.0f) * 0.5f);
    while (4 * (g + 1) * (g + 2) <= u0) ++g;
    while (4 * g * (g + 1) > u0) --g;
    int kt = u0 - 4 * g * (g + 1);
    int u = u0;

    int off = 0;
    for (int g2 = 0; g2 < g; ++g2) {
        const int j0 = (4 * g2 * (g2 + 1)) / 17;
        const int jl = (4 * (g2 + 1) * (g2 + 2) - 1) / 17;
        off += jl - j0 + 1;
    }

    // prologue: K+V tile u0 (32 chunks over 8 waves)
    {
        const size_t cb = (size_t)((b * 128 + kt) * 16) * 512;
        #pragma unroll
        for (int c4 = 0; c4 < 4; ++c4) {
            const int c = w * 4 + c4;
            const u16* gsrc = ((c < 16) ? (kfr + cb + c * 512)
                                        : (vfr + cb + (c - 16) * 512)) + lane * 8;
            gl_lds(gsrc, &buf[u0 & 1][c][0]);
        }
    }

    while (u < u1) {
        const int ktend = 8 * g + 8;
        const int rem = u1 - u;
        const int kt_stop = (ktend < kt + rem) ? ktend : (kt + rem);
        const int t0 = g * 16 + 2 * w;          // t-tile (16 q) index, 2 per wave
        const int qg0 = t0 * 16 + ln;
        const float inv0 = 1.0f / (float)(qg0 > 1 ? qg0 : 1);
        const float inv1 = 1.0f / (float)(qg0 + 16);

        bf16x8 qB0[8], qB1[8];
        {
            const u16* qb0 = qf + (size_t)(t0 * 8) * 512 + (size_t)b * (128 * 16 * 512) + lane * 8;
            #pragma unroll
            for (int ks = 0; ks < 8; ++ks) {
                qB0[ks] = *(const bf16x8*)(qb0 + ks * 512);
                qB1[ks] = *(const bf16x8*)(qb0 + (8 + ks) * 512);
            }
        }

        f32x4 oacc0[16], oacc1[16];
        #pragma unroll
        for (int dt = 0; dt < 16; ++dt) {
            oacc0[dt] = f32x4{0.f, 0.f, 0.f, 0.f};
            oacc1[dt] = f32x4{0.f, 0.f, 0.f, 0.f};
        }

        #pragma unroll 1
        for (; kt < kt_stop; ++kt, ++u) {
            const int cur = u & 1;
            __syncthreads();

            if (u + 1 < u1) {
                const int ktn = (kt + 1 < ktend) ? (kt + 1) : 0;
                const size_t cb = (size_t)((b * 128 + ktn) * 16) * 512;
                #pragma unroll
                for (int c4 = 0; c4 < 4; ++c4) {
                    const int c = w * 4 + c4;
                    const u16* gsrc = ((c < 16) ? (kfr + cb + c * 512)
                                                : (vfr + cb + (c - 16) * 512)) + lane * 8;
                    gl_lds(gsrc, &buf[cur ^ 1][c][0]);
                }
            }

            f32x4 s00 = f32x4{0.f, 0.f, 0.f, 0.f};
            f32x4 s10 = f32x4{0.f, 0.f, 0.f, 0.f};
            f32x4 s01 = f32x4{0.f, 0.f, 0.f, 0.f};
            f32x4 s11 = f32x4{0.f, 0.f, 0.f, 0.f};
            #pragma unroll
            for (int ks = 0; ks < 8; ++ks) {
                bf16x8 kf0 = *(const bf16x8*)&buf[cur][ks][lane * 8];
                bf16x8 kf1 = *(const bf16x8*)&buf[cur][8 + ks][lane * 8];
                s00 = mfma32(kf0, qB0[ks], s00);
                s10 = mfma32(kf1, qB0[ks], s10);
                s01 = mfma32(kf0, qB1[ks], s01);
                s11 = mfma32(kf1, qB1[ks], s11);
            }

            const int d0 = kt * 32 + q4 * 4 - qg0;
            float v00[4], v10[4], v01[4], v11[4];
            #pragma unroll
            for (int rr = 0; rr < 4; ++rr) {
                v00[rr] = (d0 + rr > 0)      ? 0.f : fmaxf(s00[rr], 0.f) * inv0;
                v10[rr] = (d0 + 16 + rr > 0) ? 0.f : fmaxf(s10[rr], 0.f) * inv0;
                v01[rr] = (d0 - 16 + rr > 0) ? 0.f : fmaxf(s01[rr], 0.f) * inv1;
                v11[rr] = (d0 + rr > 0)      ? 0.f : fmaxf(s11[rr], 0.f) * inv1;
            }
            union { u32x4 u; bf16x8 h; } c0, c1;
            c0.u[0] = pk2(v00[0], v00[1]); c0.u[1] = pk2(v00[2], v00[3]);
            c0.u[2] = pk2(v10[0], v10[1]); c0.u[3] = pk2(v10[2], v10[3]);
            c1.u[0] = pk2(v01[0], v01[1]); c1.u[1] = pk2(v01[2], v01[3]);
            c1.u[2] = pk2(v11[0], v11[1]); c1.u[3] = pk2(v11[2], v11[3]);

            #pragma unroll
            for (int dt = 0; dt < 16; ++dt) {
                bf16x8 vv = *(const bf16x8*)&buf[cur][16 + dt][lane * 8];
                oacc0[dt] = mfma32(vv, c0.h, oacc0[dt]);
                oacc1[dt] = mfma32(vv, c1.h, oacc1[dt]);
            }
        }

        {
            const int j0g = (4 * g * (g + 1)) / 17;
            const int gslot = off + (j - j0g);
            u16* pb0 = part + ((((size_t)b * MAXOFF + gslot) * 16 + 2 * w) * 16) * 256 + lane * 4;
            u16* pb1 = pb0 + 16 * 256;
            #pragma unroll
            for (int dt = 0; dt < 16; ++dt) {
                bf16x4 t0v, t1v;
                t0v[0] = (short)f2b(oacc0[dt][0]); t0v[1] = (short)f2b(oacc0[dt][1]);
                t0v[2] = (short)f2b(oacc0[dt][2]); t0v[3] = (short)f2b(oacc0[dt][3]);
                t1v[0] = (short)f2b(oacc1[dt][0]); t1v[1] = (short)f2b(oacc1[dt][1]);
                t1v[2] = (short)f2b(oacc1[dt][2]); t1v[3] = (short)f2b(oacc1[dt][3]);
                *(bf16x4*)(pb0 + dt * 256) = t0v;
                *(bf16x4*)(pb1 + dt * 256) = t1v;
            }
            off += ((4 * (g + 1) * (g + 2) - 1) / 17) - j0g + 1;
        }
        ++g;
        kt = 0;
    }
}

// ---------------------------------------------------------------------------
// Kernel 3: fused reduce + output projection (session-best, unchanged).
// ---------------------------------------------------------------------------
__global__ __launch_bounds__(256, 4) void oproj_kernel(
    const u16* __restrict__ part, const u16* __restrict__ wo16,
    float* __restrict__ out)
{
    __shared__ u16 cb[16 * 256];   // 8 KB

    const int w = threadIdx.x >> 6, lane = threadIdx.x & 63;
    const int q4 = lane >> 4, ln = lane & 15;
    const int g16 = blockIdx.x;        // 16-token tile, 0..1023
    const int b = g16 >> 8, gb = g16 & 255;
    const int g = gb >> 4;             // 256-query group [0,16)
    const int tloc = gb & 15;

    int off = 0;
    for (int g2 = 0; g2 < g; ++g2) {
        const int j0 = (4 * g2 * (g2 + 1)) / 17;
        const int jl = (4 * (g2 + 1) * (g2 + 2) - 1) / 17;
        off += jl - j0 + 1;
    }
    const int j0g = (4 * g * (g + 1)) / 17;
    const int jlg = (4 * (g + 1) * (g + 2) - 1) / 17;
    const int nsl = jlg - j0g + 1;

    // Phase A: 16 chunks; wave w handles 4
    #pragma unroll
    for (int c4 = 0; c4 < 4; ++c4) {
        const int dt = w * 4 + c4;
        f32x4 s = f32x4{0.f, 0.f, 0.f, 0.f};
        for (int sl = 0; sl < nsl; ++sl) {
            const u16* p = part + ((((size_t)b * MAXOFF + off + sl) * 16 + tloc) * 16 + dt) * 256 + lane * 4;
            bf16x4 pv = *(const bf16x4*)p;
            s[0] += b2f(pv[0]); s[1] += b2f(pv[1]);
            s[2] += b2f(pv[2]); s[3] += b2f(pv[3]);
        }
        bf16x4 t;
        t[0] = (short)f2b(s[0]); t[1] = (short)f2b(s[1]);
        t[2] = (short)f2b(s[2]); t[3] = (short)f2b(s[3]);
        *(bf16x4*)&cb[dt * 256 + lane * 4] = t;
    }
    __syncthreads();

    // Phase B: wave w -> d-tiles [w*4, w*4+4)
    #pragma unroll
    for (int c4 = 0; c4 < 4; ++c4) {
        const int ct = w * 4 + c4;
        f32x4 acc = f32x4{0.f, 0.f, 0.f, 0.f};
        #pragma unroll
        for (int dt = 0; dt < 16; ++dt) {
            bf16x4 A = *(const bf16x4*)(wo16 + (size_t)(ct * 16 + dt) * 256 + lane * 4);
            bf16x4 B = *(const bf16x4*)&cb[dt * 256 + lane * 4];
            acc = mfma16(A, B, acc);
        }
        float* o = out + (size_t)(g16 * 16 + ln) * DD + ct * 16 + q4 * 4;
        *(f32x4*)o = acc;
    }
}

extern "C" void kernel_launch(void* const* d_in, const int* in_sizes, int n_in,
                              void* d_out, int out_size, void* d_ws, size_t ws_size,
                              hipStream_t stream)
{
    const float* x  = (const float*)d_in[0];
    const float* Wq = (const float*)d_in[1];
    const float* Wk = (const float*)d_in[2];
    const float* Wv = (const float*)d_in[3];
    const float* Wo = (const float*)d_in[4];
    float* out = (float*)d_out;

    const size_t nW = (size_t)DD * DD;        // 65536
    const size_t nX = (size_t)BB * LL * DD;   // 4,194,304

    u16* wf   = (u16*)d_ws;                   // Wq,Wk,Wv B-frag order (384 KB)
    u16* wo16 = wf + 3 * nW;                  // Wo K=16 A-frag order (128 KB)
    u16* qfr  = wf + 4 * nW;                  // 8 MB
    u16* kfr  = qfr + nX;                     // 8 MB
    u16* vfr  = kfr + nX;                     // 8 MB
    u16* part = vfr + nX;                     // 41.9 MB (4 x 80 x 128 KB)

    wconv_kernel<<<dim3(128), dim3(256), 0, stream>>>(Wq, Wk, Wv, Wo, wf, wo16);
    qkv_kernel<<<dim3(3072), dim3(256), 0, stream>>>(x, wf, qfr, kfr, vfr);
    attn_kernel<<<dim3(256), dim3(512), 0, stream>>>(qfr, kfr, vfr, part);
    oproj_kernel<<<dim3(1024), dim3(256), 0, stream>>>(part, wo16, out);
}

// Round 15
// 153.923 us; speedup vs baseline: 1.0741x; 1.0741x over previous
//
#include <hip/hip_runtime.h>

#define BB 4
#define LL 4096
#define DD 256
#define MAXOFF 80    // max per-batch partial slots (exact bound: 78), slot = 256q x 256d

typedef short bf16x8 __attribute__((ext_vector_type(8)));
typedef short bf16x4 __attribute__((ext_vector_type(4)));
typedef float f32x4 __attribute__((ext_vector_type(4)));
typedef unsigned u32x4 __attribute__((ext_vector_type(4)));
typedef unsigned short u16;

__device__ inline u16 f2b(float f) {
    union { float f; unsigned u; } v; v.f = f;
    unsigned r = (v.u + 0x7fffu + ((v.u >> 16) & 1u)) >> 16;  // RNE
    return (u16)r;
}
__device__ inline float b2f(short s) {
    union { unsigned u; float f; } v; v.u = ((unsigned)(unsigned short)s) << 16;
    return v.f;
}
// pack 2 fp32 -> 2 bf16 (TRUNCATE) in one v_perm_b32
__device__ inline unsigned pk2(float lo, float hi) {
    union { float f; unsigned u; } a, b; a.f = lo; b.f = hi;
    return __builtin_amdgcn_perm(b.u, a.u, 0x07060302u);
}

__device__ inline f32x4 mfma32(bf16x8 a, bf16x8 b, f32x4 c) {
    return __builtin_amdgcn_mfma_f32_16x16x32_bf16(a, b, c, 0, 0, 0);
}
__device__ inline f32x4 mfma16(bf16x4 a, bf16x4 b, f32x4 c) {
    return __builtin_amdgcn_mfma_f32_16x16x16bf16_1k(a, b, c, 0, 0, 0);
}

__device__ inline void gl_lds(const u16* g, u16* l) {
    __builtin_amdgcn_global_load_lds(
        (const __attribute__((address_space(1))) void*)g,
        (__attribute__((address_space(3))) void*)l, 16, 0, 0);
}

// ===========================================================================
// FINAL: session-best configuration (measured 153.9 / 152.9 / 154.8 us).
//
// Measured search summary (14 rounds, all alternatives falsified):
//   attn: dbuf+syncthreads 43.3 BEST | PV-pipeline 53 | 64q/wave@1wave 80 |
//         2 blk/CU 48 | KVBLK=64 44.2 | triple-buffer counted-vmcnt 55
//   qkv:  1024x256@4/CU BEST | 512x512@2/CU +11us | 3072x256@5/CU split +10us
//   oproj/wconv: in every best measurement; never dominant.
// Timed window ~153us = harness ws-poison fill ~44 + attn ~44 + qkv/oproj/
// wconv/gaps ~65. attn MfmaUtil 31%/HBM 19% is a structural plateau of the
// query-split LDS-broadcast decomposition at HIP source level (m131-m141);
// beyond it lies producer-consumer wave specialization / inline-asm K-loop.
// ===========================================================================

__global__ __launch_bounds__(256) void wconv_kernel(
    const float* __restrict__ Wq, const float* __restrict__ Wk,
    const float* __restrict__ Wv, const float* __restrict__ Wo,
    u16* __restrict__ wf, u16* __restrict__ wo16)
{
    const int w = threadIdx.x >> 6, lane = threadIdx.x & 63;
    const int q4 = lane >> 4, ln = lane & 15;
    const int id = blockIdx.x * 4 + w;          // 0..511
    const int mat = id >> 7, rem = id & 127, ct = rem >> 3, ks = rem & 7;
    if (mat < 3) {
        const float* W = (mat == 0) ? Wq : (mat == 1) ? Wk : Wv;
        const float* src = W + (size_t)(ct * 16 + ln) * DD + ks * 32 + q4 * 8;
        float4 f0 = ((const float4*)src)[0], f1 = ((const float4*)src)[1];
        bf16x8 t;
        t[0] = (short)f2b(f0.x); t[1] = (short)f2b(f0.y);
        t[2] = (short)f2b(f0.z); t[3] = (short)f2b(f0.w);
        t[4] = (short)f2b(f1.x); t[5] = (short)f2b(f1.y);
        t[6] = (short)f2b(f1.z); t[7] = (short)f2b(f1.w);
        *(bf16x8*)(wf + (size_t)mat * 65536 + (ct * 8 + ks) * 512 + lane * 8) = t;
    } else {
        const float* src = Wo + (size_t)(ct * 16 + ln) * DD + ks * 32 + q4 * 4;
        float4 f0 = *(const float4*)src;
        float4 f1 = *(const float4*)(src + 16);
        bf16x4 t0, t1;
        t0[0] = (short)f2b(f0.x); t0[1] = (short)f2b(f0.y);
        t0[2] = (short)f2b(f0.z); t0[3] = (short)f2b(f0.w);
        t1[0] = (short)f2b(f1.x); t1[1] = (short)f2b(f1.y);
        t1[2] = (short)f2b(f1.z); t1[3] = (short)f2b(f1.w);
        *(bf16x4*)(wo16 + (size_t)(ct * 16 + 2 * ks) * 256 + lane * 4) = t0;
        *(bf16x4*)(wo16 + (size_t)(ct * 16 + 2 * ks + 1) * 256 + lane * 4) = t1;
    }
}

// ---------------------------------------------------------------------------
// Kernel 1: QKV projection (1024 blocks x 256 thr, 4/CU).
// ---------------------------------------------------------------------------
__global__ __launch_bounds__(256, 4) void qkv_kernel(
    const float* __restrict__ x, const u16* __restrict__ wf,
    u16* __restrict__ qf, u16* __restrict__ kf_, u16* __restrict__ vf_)
{
    __shared__ u16 lt_q[32 * 136];   // [token 32][dim_local 128 +pad]
    __shared__ u16 lt_k[32 * 136];
    __shared__ u16 lt_v[128 * 40];   // [dim_local 128][token 32 +pad]

    const int w = threadIdx.x >> 6, lane = threadIdx.x & 63;
    const int q4 = lane >> 4, ln = lane & 15;
    const int tg = blockIdx.x >> 1, half = blockIdx.x & 1;
    const int tl = w & 1, dq = w >> 1;

    // A-frags: 16 token rows (fp32 -> bf16)
    bf16x8 a[8];
    {
        const float* xrow = x + (size_t)(tg * 32 + tl * 16 + ln) * DD;
        #pragma unroll
        for (int ks = 0; ks < 8; ++ks) {
            const float4* p = (const float4*)(xrow + ks * 32 + q4 * 8);
            float4 f0 = p[0], f1 = p[1];
            bf16x8 t;
            t[0] = (short)f2b(f0.x); t[1] = (short)f2b(f0.y);
            t[2] = (short)f2b(f0.z); t[3] = (short)f2b(f0.w);
            t[4] = (short)f2b(f1.x); t[5] = (short)f2b(f1.y);
            t[6] = (short)f2b(f1.z); t[7] = (short)f2b(f1.w);
            a[ks] = t;
        }
    }

    f32x4 acc0[4], acc1[4], acc2[4];
    #pragma unroll
    for (int cl = 0; cl < 4; ++cl) {
        acc0[cl] = f32x4{0.f, 0.f, 0.f, 0.f};
        acc1[cl] = f32x4{0.f, 0.f, 0.f, 0.f};
        acc2[cl] = f32x4{0.f, 0.f, 0.f, 0.f};
    }

    #pragma unroll
    for (int ks = 0; ks < 8; ++ks) {
        #pragma unroll
        for (int cl = 0; cl < 4; ++cl) {
            const int ct = half * 8 + dq * 4 + cl;
            const size_t off = ((size_t)ct * 8 + ks) * 512 + lane * 8;
            bf16x8 b0 = *(const bf16x8*)(wf + off);
            bf16x8 b1 = *(const bf16x8*)(wf + 65536 + off);
            bf16x8 b2 = *(const bf16x8*)(wf + 131072 + off);
            acc0[cl] = mfma32(a[ks], b0, acc0[cl]);
            acc1[cl] = mfma32(a[ks], b1, acc1[cl]);
            acc2[cl] = mfma32(a[ks], b2, acc2[cl]);
        }
    }

    // C-layout -> LDS (disjoint regions; single barrier after)
    #pragma unroll
    for (int cl = 0; cl < 4; ++cl) {
        const int coll = (dq * 4 + cl) * 16 + ln;   // local dim [0,128)
        #pragma unroll
        for (int r = 0; r < 4; ++r) {
            const int tok = tl * 16 + q4 * 4 + r;   // local token [0,32)
            lt_q[tok * 136 + coll] = f2b(acc0[cl][r]);
            lt_k[tok * 136 + coll] = f2b(acc1[cl][r]);
            lt_v[coll * 40 + tok] = f2b(acc2[cl][r]);
        }
    }
    __syncthreads();

    // Q/K: wave w -> h = w&1, ksl in {2*dq, 2*dq+1}
    {
        const int h = w & 1;
        #pragma unroll
        for (int e = 0; e < 2; ++e) {
            const int ksl = 2 * dq + e;             // local K-chunk [0,4)
            const int ks = half * 4 + ksl;          // global K-chunk [0,8)
            bf16x8 aq = *(const bf16x8*)&lt_q[(h * 16 + ln) * 136 + ksl * 32 + q4 * 8];
            bf16x8 ak = *(const bf16x8*)&lt_k[(h * 16 + ln) * 136 + ksl * 32 + q4 * 8];
            const size_t dst = (size_t)((tg * 2 + h) * 8 + ks) * 512 + lane * 8;
            *(bf16x8*)(qf + dst) = aq;
            *(bf16x8*)(kf_ + dst) = ak;
        }
    }
    // V: wave w -> dt_l in {2w, 2w+1}
    #pragma unroll
    for (int e = 0; e < 2; ++e) {
        const int dt_l = 2 * w + e;                 // local d-tile [0,8)
        bf16x4 lo = *(const bf16x4*)&lt_v[(dt_l * 16 + ln) * 40 + q4 * 4];
        bf16x4 hi = *(const bf16x4*)&lt_v[(dt_l * 16 + ln) * 40 + 16 + q4 * 4];
        bf16x8 t;
        t[0] = lo[0]; t[1] = lo[1]; t[2] = lo[2]; t[3] = lo[3];
        t[4] = hi[0]; t[5] = hi[1]; t[6] = hi[2]; t[7] = hi[3];
        *(bf16x8*)(vf_ + (size_t)(tg * 16 + half * 8 + dt_l) * 512 + lane * 8) = t;
    }
}

// ---------------------------------------------------------------------------
// Kernel 2: causal ReLU attention. 256-query groups, 8 waves x 32 queries,
// 256 blocks x 512 threads, 64KB LDS dbuf, 17 u-steps/block, XCD decode.
// ---------------------------------------------------------------------------
__global__ __launch_bounds__(512, 2) void attn_kernel(
    const u16* __restrict__ qf, const u16* __restrict__ kfr,
    const u16* __restrict__ vfr, u16* __restrict__ part)
{
    __shared__ u16 buf[2][32][512];   // 64 KB: K (chunks 0-15) + V (16-31), dbuf

    const int id = blockIdx.x;                  // 0..255
    const int xcd = id & 7;
    const int b = xcd >> 1;                     // 2 XCDs per batch
    const int j = ((xcd & 1) << 5) | (id >> 3); // segment 0..63

    const int w = threadIdx.x >> 6, lane = threadIdx.x & 63;
    const int q4 = lane >> 4, ln = lane & 15;

    const int u0 = 17 * j;
    const int u1 = u0 + 17;

    int g = (int)((sqrtf((float)u0 + 1.0f) - 1.0f) * 0.5f);
    while (4 * (g + 1) * (g + 2) <= u0) ++g;
    while (4 * g * (g + 1) > u0) --g;
    int kt = u0 - 4 * g * (g + 1);
    int u = u0;

    int off = 0;
    for (int g2 = 0; g2 < g; ++g2) {
        const int j0 = (4 * g2 * (g2 + 1)) / 17;
        const int jl = (4 * (g2 + 1) * (g2 + 2) - 1) / 17;
        off += jl - j0 + 1;
    }

    // prologue: K+V tile u0 (32 chunks over 8 waves)
    {
        const size_t cb = (size_t)((b * 128 + kt) * 16) * 512;
        #pragma unroll
        for (int c4 = 0; c4 < 4; ++c4) {
            const int c = w * 4 + c4;
            const u16* gsrc = ((c < 16) ? (kfr + cb + c * 512)
                                        : (vfr + cb + (c - 16) * 512)) + lane * 8;
            gl_lds(gsrc, &buf[u0 & 1][c][0]);
        }
    }

    while (u < u1) {
        const int ktend = 8 * g + 8;
        const int rem = u1 - u;
        const int kt_stop = (ktend < kt + rem) ? ktend : (kt + rem);
        const int t0 = g * 16 + 2 * w;          // t-tile (16 q) index, 2 per wave
        const int qg0 = t0 * 16 + ln;
        const float inv0 = 1.0f / (float)(qg0 > 1 ? qg0 : 1);
        const float inv1 = 1.0f / (float)(qg0 + 16);

        bf16x8 qB0[8], qB1[8];
        {
            const u16* qb0 = qf + (size_t)(t0 * 8) * 512 + (size_t)b * (128 * 16 * 512) + lane * 8;
            #pragma unroll
            for (int ks = 0; ks < 8; ++ks) {
                qB0[ks] = *(const bf16x8*)(qb0 + ks * 512);
                qB1[ks] = *(const bf16x8*)(qb0 + (8 + ks) * 512);
            }
        }

        f32x4 oacc0[16], oacc1[16];
        #pragma unroll
        for (int dt = 0; dt < 16; ++dt) {
            oacc0[dt] = f32x4{0.f, 0.f, 0.f, 0.f};
            oacc1[dt] = f32x4{0.f, 0.f, 0.f, 0.f};
        }

        #pragma unroll 1
        for (; kt < kt_stop; ++kt, ++u) {
            const int cur = u & 1;
            __syncthreads();

            if (u + 1 < u1) {
                const int ktn = (kt + 1 < ktend) ? (kt + 1) : 0;
                const size_t cb = (size_t)((b * 128 + ktn) * 16) * 512;
                #pragma unroll
                for (int c4 = 0; c4 < 4; ++c4) {
                    const int c = w * 4 + c4;
                    const u16* gsrc = ((c < 16) ? (kfr + cb + c * 512)
                                                : (vfr + cb + (c - 16) * 512)) + lane * 8;
                    gl_lds(gsrc, &buf[cur ^ 1][c][0]);
                }
            }

            f32x4 s00 = f32x4{0.f, 0.f, 0.f, 0.f};
            f32x4 s10 = f32x4{0.f, 0.f, 0.f, 0.f};
            f32x4 s01 = f32x4{0.f, 0.f, 0.f, 0.f};
            f32x4 s11 = f32x4{0.f, 0.f, 0.f, 0.f};
            #pragma unroll
            for (int ks = 0; ks < 8; ++ks) {
                bf16x8 kf0 = *(const bf16x8*)&buf[cur][ks][lane * 8];
                bf16x8 kf1 = *(const bf16x8*)&buf[cur][8 + ks][lane * 8];
                s00 = mfma32(kf0, qB0[ks], s00);
                s10 = mfma32(kf1, qB0[ks], s10);
                s01 = mfma32(kf0, qB1[ks], s01);
                s11 = mfma32(kf1, qB1[ks], s11);
            }

            const int d0 = kt * 32 + q4 * 4 - qg0;
            float v00[4], v10[4], v01[4], v11[4];
            #pragma unroll
            for (int rr = 0; rr < 4; ++rr) {
                v00[rr] = (d0 + rr > 0)      ? 0.f : fmaxf(s00[rr], 0.f) * inv0;
                v10[rr] = (d0 + 16 + rr > 0) ? 0.f : fmaxf(s10[rr], 0.f) * inv0;
                v01[rr] = (d0 - 16 + rr > 0) ? 0.f : fmaxf(s01[rr], 0.f) * inv1;
                v11[rr] = (d0 + rr > 0)      ? 0.f : fmaxf(s11[rr], 0.f) * inv1;
            }
            union { u32x4 u; bf16x8 h; } c0, c1;
            c0.u[0] = pk2(v00[0], v00[1]); c0.u[1] = pk2(v00[2], v00[3]);
            c0.u[2] = pk2(v10[0], v10[1]); c0.u[3] = pk2(v10[2], v10[3]);
            c1.u[0] = pk2(v01[0], v01[1]); c1.u[1] = pk2(v01[2], v01[3]);
            c1.u[2] = pk2(v11[0], v11[1]); c1.u[3] = pk2(v11[2], v11[3]);

            #pragma unroll
            for (int dt = 0; dt < 16; ++dt) {
                bf16x8 vv = *(const bf16x8*)&buf[cur][16 + dt][lane * 8];
                oacc0[dt] = mfma32(vv, c0.h, oacc0[dt]);
                oacc1[dt] = mfma32(vv, c1.h, oacc1[dt]);
            }
        }

        {
            const int j0g = (4 * g * (g + 1)) / 17;
            const int gslot = off + (j - j0g);
            u16* pb0 = part + ((((size_t)b * MAXOFF + gslot) * 16 + 2 * w) * 16) * 256 + lane * 4;
            u16* pb1 = pb0 + 16 * 256;
            #pragma unroll
            for (int dt = 0; dt < 16; ++dt) {
                bf16x4 t0v, t1v;
                t0v[0] = (short)f2b(oacc0[dt][0]); t0v[1] = (short)f2b(oacc0[dt][1]);
                t0v[2] = (short)f2b(oacc0[dt][2]); t0v[3] = (short)f2b(oacc0[dt][3]);
                t1v[0] = (short)f2b(oacc1[dt][0]); t1v[1] = (short)f2b(oacc1[dt][1]);
                t1v[2] = (short)f2b(oacc1[dt][2]); t1v[3] = (short)f2b(oacc1[dt][3]);
                *(bf16x4*)(pb0 + dt * 256) = t0v;
                *(bf16x4*)(pb1 + dt * 256) = t1v;
            }
            off += ((4 * (g + 1) * (g + 2) - 1) / 17) - j0g + 1;
        }
        ++g;
        kt = 0;
    }
}

// ---------------------------------------------------------------------------
// Kernel 3: fused reduce + output projection (1024 blocks x 256 thr).
// ---------------------------------------------------------------------------
__global__ __launch_bounds__(256, 4) void oproj_kernel(
    const u16* __restrict__ part, const u16* __restrict__ wo16,
    float* __restrict__ out)
{
    __shared__ u16 cb[16 * 256];   // 8 KB

    const int w = threadIdx.x >> 6, lane = threadIdx.x & 63;
    const int q4 = lane >> 4, ln = lane & 15;
    const int g16 = blockIdx.x;        // 16-token tile, 0..1023
    const int b = g16 >> 8, gb = g16 & 255;
    const int g = gb >> 4;             // 256-query group [0,16)
    const int tloc = gb & 15;

    int off = 0;
    for (int g2 = 0; g2 < g; ++g2) {
        const int j0 = (4 * g2 * (g2 + 1)) / 17;
        const int jl = (4 * (g2 + 1) * (g2 + 2) - 1) / 17;
        off += jl - j0 + 1;
    }
    const int j0g = (4 * g * (g + 1)) / 17;
    const int jlg = (4 * (g + 1) * (g + 2) - 1) / 17;
    const int nsl = jlg - j0g + 1;

    // Phase A: 16 chunks; wave w handles 4
    #pragma unroll
    for (int c4 = 0; c4 < 4; ++c4) {
        const int dt = w * 4 + c4;
        f32x4 s = f32x4{0.f, 0.f, 0.f, 0.f};
        for (int sl = 0; sl < nsl; ++sl) {
            const u16* p = part + ((((size_t)b * MAXOFF + off + sl) * 16 + tloc) * 16 + dt) * 256 + lane * 4;
            bf16x4 pv = *(const bf16x4*)p;
            s[0] += b2f(pv[0]); s[1] += b2f(pv[1]);
            s[2] += b2f(pv[2]); s[3] += b2f(pv[3]);
        }
        bf16x4 t;
        t[0] = (short)f2b(s[0]); t[1] = (short)f2b(s[1]);
        t[2] = (short)f2b(s[2]); t[3] = (short)f2b(s[3]);
        *(bf16x4*)&cb[dt * 256 + lane * 4] = t;
    }
    __syncthreads();

    // Phase B: wave w -> d-tiles [w*4, w*4+4)
    #pragma unroll
    for (int c4 = 0; c4 < 4; ++c4) {
        const int ct = w * 4 + c4;
        f32x4 acc = f32x4{0.f, 0.f, 0.f, 0.f};
        #pragma unroll
        for (int dt = 0; dt < 16; ++dt) {
            bf16x4 A = *(const bf16x4*)(wo16 + (size_t)(ct * 16 + dt) * 256 + lane * 4);
            bf16x4 B = *(const bf16x4*)&cb[dt * 256 + lane * 4];
            acc = mfma16(A, B, acc);
        }
        float* o = out + (size_t)(g16 * 16 + ln) * DD + ct * 16 + q4 * 4;
        *(f32x4*)o = acc;
    }
}

extern "C" void kernel_launch(void* const* d_in, const int* in_sizes, int n_in,
                              void* d_out, int out_size, void* d_ws, size_t ws_size,
                              hipStream_t stream)
{
    const float* x  = (const float*)d_in[0];
    const float* Wq = (const float*)d_in[1];
    const float* Wk = (const float*)d_in[2];
    const float* Wv = (const float*)d_in[3];
    const float* Wo = (const float*)d_in[4];
    float* out = (float*)d_out;

    const size_t nW = (size_t)DD * DD;        // 65536
    const size_t nX = (size_t)BB * LL * DD;   // 4,194,304

    u16* wf   = (u16*)d_ws;                   // Wq,Wk,Wv B-frag order (384 KB)
    u16* wo16 = wf + 3 * nW;                  // Wo K=16 A-frag order (128 KB)
    u16* qfr  = wf + 4 * nW;                  // 8 MB
    u16* kfr  = qfr + nX;                     // 8 MB
    u16* vfr  = kfr + nX;                     // 8 MB
    u16* part = vfr + nX;                     // 41.9 MB (4 x 80 x 128 KB)

    wconv_kernel<<<dim3(128), dim3(256), 0, stream>>>(Wq, Wk, Wv, Wo, wf, wo16);
    qkv_kernel<<<dim3(1024), dim3(256), 0, stream>>>(x, wf, qfr, kfr, vfr);
    attn_kernel<<<dim3(256), dim3(512), 0, stream>>>(qfr, kfr, vfr, part);
    oproj_kernel<<<dim3(1024), dim3(256), 0, stream>>>(part, wo16, out);
}

// Round 16
// 150.782 us; speedup vs baseline: 1.0965x; 1.0208x over previous
//
#include <hip/hip_runtime.h>

#define BB 4
#define LL 4096
#define DD 256
#define MAXOFF 80    // max per-batch partial slots (exact bound: 78), slot = 256q x 256d

typedef short bf16x8 __attribute__((ext_vector_type(8)));
typedef short bf16x4 __attribute__((ext_vector_type(4)));
typedef float f32x4 __attribute__((ext_vector_type(4)));
typedef unsigned u32x4 __attribute__((ext_vector_type(4)));
typedef unsigned short u16;

__device__ inline u16 f2b(float f) {
    union { float f; unsigned u; } v; v.f = f;
    unsigned r = (v.u + 0x7fffu + ((v.u >> 16) & 1u)) >> 16;  // RNE
    return (u16)r;
}
__device__ inline float b2f(short s) {
    union { unsigned u; float f; } v; v.u = ((unsigned)(unsigned short)s) << 16;
    return v.f;
}
// pack 2 fp32 -> 2 bf16 (TRUNCATE) in one v_perm_b32
__device__ inline unsigned pk2(float lo, float hi) {
    union { float f; unsigned u; } a, b; a.f = lo; b.f = hi;
    return __builtin_amdgcn_perm(b.u, a.u, 0x07060302u);
}

__device__ inline f32x4 mfma32(bf16x8 a, bf16x8 b, f32x4 c) {
    return __builtin_amdgcn_mfma_f32_16x16x32_bf16(a, b, c, 0, 0, 0);
}
__device__ inline f32x4 mfma16(bf16x4 a, bf16x4 b, f32x4 c) {
    return __builtin_amdgcn_mfma_f32_16x16x16bf16_1k(a, b, c, 0, 0, 0);
}

__device__ inline void gl_lds(const u16* g, u16* l) {
    __builtin_amdgcn_global_load_lds(
        (const __attribute__((address_space(1))) void*)g,
        (__attribute__((address_space(3))) void*)l, 16, 0, 0);
}

// ===========================================================================
// Round 28: session-best config (153.9/152.9/154.8/153.9 us, 4x reproduced)
// + ONE change: oproj group decode batch-rotated, g = ((gb>>4) + 4b) & 15.
// Why: oproj per-block Phase-A work is nsl(g) in {1..8}; with 1024 blocks at
// exactly 4/CU and round-robin dispatch, CU c hosts blocks {c,c+256,c+512,
// c+768} which share gb=c&255 -> SAME g -> per-CU slot totals range 4..32
// (8x spread); kernel ends when heavy CUs finish. The rotation is a bijection
// per batch (every (b,g,tloc) computed exactly once) that mixes g values
// {g,g+4,g+8,g+12} on each CU -> per-CU totals flatten to 18..22.
// attn/qkv/wconv byte-identical to the 4x-reproduced best source.
// ===========================================================================

__global__ __launch_bounds__(256) void wconv_kernel(
    const float* __restrict__ Wq, const float* __restrict__ Wk,
    const float* __restrict__ Wv, const float* __restrict__ Wo,
    u16* __restrict__ wf, u16* __restrict__ wo16)
{
    const int w = threadIdx.x >> 6, lane = threadIdx.x & 63;
    const int q4 = lane >> 4, ln = lane & 15;
    const int id = blockIdx.x * 4 + w;          // 0..511
    const int mat = id >> 7, rem = id & 127, ct = rem >> 3, ks = rem & 7;
    if (mat < 3) {
        const float* W = (mat == 0) ? Wq : (mat == 1) ? Wk : Wv;
        const float* src = W + (size_t)(ct * 16 + ln) * DD + ks * 32 + q4 * 8;
        float4 f0 = ((const float4*)src)[0], f1 = ((const float4*)src)[1];
        bf16x8 t;
        t[0] = (short)f2b(f0.x); t[1] = (short)f2b(f0.y);
        t[2] = (short)f2b(f0.z); t[3] = (short)f2b(f0.w);
        t[4] = (short)f2b(f1.x); t[5] = (short)f2b(f1.y);
        t[6] = (short)f2b(f1.z); t[7] = (short)f2b(f1.w);
        *(bf16x8*)(wf + (size_t)mat * 65536 + (ct * 8 + ks) * 512 + lane * 8) = t;
    } else {
        const float* src = Wo + (size_t)(ct * 16 + ln) * DD + ks * 32 + q4 * 4;
        float4 f0 = *(const float4*)src;
        float4 f1 = *(const float4*)(src + 16);
        bf16x4 t0, t1;
        t0[0] = (short)f2b(f0.x); t0[1] = (short)f2b(f0.y);
        t0[2] = (short)f2b(f0.z); t0[3] = (short)f2b(f0.w);
        t1[0] = (short)f2b(f1.x); t1[1] = (short)f2b(f1.y);
        t1[2] = (short)f2b(f1.z); t1[3] = (short)f2b(f1.w);
        *(bf16x4*)(wo16 + (size_t)(ct * 16 + 2 * ks) * 256 + lane * 4) = t0;
        *(bf16x4*)(wo16 + (size_t)(ct * 16 + 2 * ks + 1) * 256 + lane * 4) = t1;
    }
}

// ---------------------------------------------------------------------------
// Kernel 1: QKV projection (1024 blocks x 256 thr, 4/CU).
// ---------------------------------------------------------------------------
__global__ __launch_bounds__(256, 4) void qkv_kernel(
    const float* __restrict__ x, const u16* __restrict__ wf,
    u16* __restrict__ qf, u16* __restrict__ kf_, u16* __restrict__ vf_)
{
    __shared__ u16 lt_q[32 * 136];   // [token 32][dim_local 128 +pad]
    __shared__ u16 lt_k[32 * 136];
    __shared__ u16 lt_v[128 * 40];   // [dim_local 128][token 32 +pad]

    const int w = threadIdx.x >> 6, lane = threadIdx.x & 63;
    const int q4 = lane >> 4, ln = lane & 15;
    const int tg = blockIdx.x >> 1, half = blockIdx.x & 1;
    const int tl = w & 1, dq = w >> 1;

    // A-frags: 16 token rows (fp32 -> bf16)
    bf16x8 a[8];
    {
        const float* xrow = x + (size_t)(tg * 32 + tl * 16 + ln) * DD;
        #pragma unroll
        for (int ks = 0; ks < 8; ++ks) {
            const float4* p = (const float4*)(xrow + ks * 32 + q4 * 8);
            float4 f0 = p[0], f1 = p[1];
            bf16x8 t;
            t[0] = (short)f2b(f0.x); t[1] = (short)f2b(f0.y);
            t[2] = (short)f2b(f0.z); t[3] = (short)f2b(f0.w);
            t[4] = (short)f2b(f1.x); t[5] = (short)f2b(f1.y);
            t[6] = (short)f2b(f1.z); t[7] = (short)f2b(f1.w);
            a[ks] = t;
        }
    }

    f32x4 acc0[4], acc1[4], acc2[4];
    #pragma unroll
    for (int cl = 0; cl < 4; ++cl) {
        acc0[cl] = f32x4{0.f, 0.f, 0.f, 0.f};
        acc1[cl] = f32x4{0.f, 0.f, 0.f, 0.f};
        acc2[cl] = f32x4{0.f, 0.f, 0.f, 0.f};
    }

    #pragma unroll
    for (int ks = 0; ks < 8; ++ks) {
        #pragma unroll
        for (int cl = 0; cl < 4; ++cl) {
            const int ct = half * 8 + dq * 4 + cl;
            const size_t off = ((size_t)ct * 8 + ks) * 512 + lane * 8;
            bf16x8 b0 = *(const bf16x8*)(wf + off);
            bf16x8 b1 = *(const bf16x8*)(wf + 65536 + off);
            bf16x8 b2 = *(const bf16x8*)(wf + 131072 + off);
            acc0[cl] = mfma32(a[ks], b0, acc0[cl]);
            acc1[cl] = mfma32(a[ks], b1, acc1[cl]);
            acc2[cl] = mfma32(a[ks], b2, acc2[cl]);
        }
    }

    // C-layout -> LDS (disjoint regions; single barrier after)
    #pragma unroll
    for (int cl = 0; cl < 4; ++cl) {
        const int coll = (dq * 4 + cl) * 16 + ln;   // local dim [0,128)
        #pragma unroll
        for (int r = 0; r < 4; ++r) {
            const int tok = tl * 16 + q4 * 4 + r;   // local token [0,32)
            lt_q[tok * 136 + coll] = f2b(acc0[cl][r]);
            lt_k[tok * 136 + coll] = f2b(acc1[cl][r]);
            lt_v[coll * 40 + tok] = f2b(acc2[cl][r]);
        }
    }
    __syncthreads();

    // Q/K: wave w -> h = w&1, ksl in {2*dq, 2*dq+1}
    {
        const int h = w & 1;
        #pragma unroll
        for (int e = 0; e < 2; ++e) {
            const int ksl = 2 * dq + e;             // local K-chunk [0,4)
            const int ks = half * 4 + ksl;          // global K-chunk [0,8)
            bf16x8 aq = *(const bf16x8*)&lt_q[(h * 16 + ln) * 136 + ksl * 32 + q4 * 8];
            bf16x8 ak = *(const bf16x8*)&lt_k[(h * 16 + ln) * 136 + ksl * 32 + q4 * 8];
            const size_t dst = (size_t)((tg * 2 + h) * 8 + ks) * 512 + lane * 8;
            *(bf16x8*)(qf + dst) = aq;
            *(bf16x8*)(kf_ + dst) = ak;
        }
    }
    // V: wave w -> dt_l in {2w, 2w+1}
    #pragma unroll
    for (int e = 0; e < 2; ++e) {
        const int dt_l = 2 * w + e;                 // local d-tile [0,8)
        bf16x4 lo = *(const bf16x4*)&lt_v[(dt_l * 16 + ln) * 40 + q4 * 4];
        bf16x4 hi = *(const bf16x4*)&lt_v[(dt_l * 16 + ln) * 40 + 16 + q4 * 4];
        bf16x8 t;
        t[0] = lo[0]; t[1] = lo[1]; t[2] = lo[2]; t[3] = lo[3];
        t[4] = hi[0]; t[5] = hi[1]; t[6] = hi[2]; t[7] = hi[3];
        *(bf16x8*)(vf_ + (size_t)(tg * 16 + half * 8 + dt_l) * 512 + lane * 8) = t;
    }
}

// ---------------------------------------------------------------------------
// Kernel 2: causal ReLU attention. 256-query groups, 8 waves x 32 queries,
// 256 blocks x 512 threads, 64KB LDS dbuf, 17 u-steps/block, XCD decode.
// ---------------------------------------------------------------------------
__global__ __launch_bounds__(512, 2) void attn_kernel(
    const u16* __restrict__ qf, const u16* __restrict__ kfr,
    const u16* __restrict__ vfr, u16* __restrict__ part)
{
    __shared__ u16 buf[2][32][512];   // 64 KB: K (chunks 0-15) + V (16-31), dbuf

    const int id = blockIdx.x;                  // 0..255
    const int xcd = id & 7;
    const int b = xcd >> 1;                     // 2 XCDs per batch
    const int j = ((xcd & 1) << 5) | (id >> 3); // segment 0..63

    const int w = threadIdx.x >> 6, lane = threadIdx.x & 63;
    const int q4 = lane >> 4, ln = lane & 15;

    const int u0 = 17 * j;
    const int u1 = u0 + 17;

    int g = (int)((sqrtf((float)u0 + 1.0f) - 1.0f) * 0.5f);
    while (4 * (g + 1) * (g + 2) <= u0) ++g;
    while (4 * g * (g + 1) > u0) --g;
    int kt = u0 - 4 * g * (g + 1);
    int u = u0;

    int off = 0;
    for (int g2 = 0; g2 < g; ++g2) {
        const int j0 = (4 * g2 * (g2 + 1)) / 17;
        const int jl = (4 * (g2 + 1) * (g2 + 2) - 1) / 17;
        off += jl - j0 + 1;
    }

    // prologue: K+V tile u0 (32 chunks over 8 waves)
    {
        const size_t cb = (size_t)((b * 128 + kt) * 16) * 512;
        #pragma unroll
        for (int c4 = 0; c4 < 4; ++c4) {
            const int c = w * 4 + c4;
            const u16* gsrc = ((c < 16) ? (kfr + cb + c * 512)
                                        : (vfr + cb + (c - 16) * 512)) + lane * 8;
            gl_lds(gsrc, &buf[u0 & 1][c][0]);
        }
    }

    while (u < u1) {
        const int ktend = 8 * g + 8;
        const int rem = u1 - u;
        const int kt_stop = (ktend < kt + rem) ? ktend : (kt + rem);
        const int t0 = g * 16 + 2 * w;          // t-tile (16 q) index, 2 per wave
        const int qg0 = t0 * 16 + ln;
        const float inv0 = 1.0f / (float)(qg0 > 1 ? qg0 : 1);
        const float inv1 = 1.0f / (float)(qg0 + 16);

        bf16x8 qB0[8], qB1[8];
        {
            const u16* qb0 = qf + (size_t)(t0 * 8) * 512 + (size_t)b * (128 * 16 * 512) + lane * 8;
            #pragma unroll
            for (int ks = 0; ks < 8; ++ks) {
                qB0[ks] = *(const bf16x8*)(qb0 + ks * 512);
                qB1[ks] = *(const bf16x8*)(qb0 + (8 + ks) * 512);
            }
        }

        f32x4 oacc0[16], oacc1[16];
        #pragma unroll
        for (int dt = 0; dt < 16; ++dt) {
            oacc0[dt] = f32x4{0.f, 0.f, 0.f, 0.f};
            oacc1[dt] = f32x4{0.f, 0.f, 0.f, 0.f};
        }

        #pragma unroll 1
        for (; kt < kt_stop; ++kt, ++u) {
            const int cur = u & 1;
            __syncthreads();

            if (u + 1 < u1) {
                const int ktn = (kt + 1 < ktend) ? (kt + 1) : 0;
                const size_t cb = (size_t)((b * 128 + ktn) * 16) * 512;
                #pragma unroll
                for (int c4 = 0; c4 < 4; ++c4) {
                    const int c = w * 4 + c4;
                    const u16* gsrc = ((c < 16) ? (kfr + cb + c * 512)
                                                : (vfr + cb + (c - 16) * 512)) + lane * 8;
                    gl_lds(gsrc, &buf[cur ^ 1][c][0]);
                }
            }

            f32x4 s00 = f32x4{0.f, 0.f, 0.f, 0.f};
            f32x4 s10 = f32x4{0.f, 0.f, 0.f, 0.f};
            f32x4 s01 = f32x4{0.f, 0.f, 0.f, 0.f};
            f32x4 s11 = f32x4{0.f, 0.f, 0.f, 0.f};
            #pragma unroll
            for (int ks = 0; ks < 8; ++ks) {
                bf16x8 kf0 = *(const bf16x8*)&buf[cur][ks][lane * 8];
                bf16x8 kf1 = *(const bf16x8*)&buf[cur][8 + ks][lane * 8];
                s00 = mfma32(kf0, qB0[ks], s00);
                s10 = mfma32(kf1, qB0[ks], s10);
                s01 = mfma32(kf0, qB1[ks], s01);
                s11 = mfma32(kf1, qB1[ks], s11);
            }

            const int d0 = kt * 32 + q4 * 4 - qg0;
            float v00[4], v10[4], v01[4], v11[4];
            #pragma unroll
            for (int rr = 0; rr < 4; ++rr) {
                v00[rr] = (d0 + rr > 0)      ? 0.f : fmaxf(s00[rr], 0.f) * inv0;
                v10[rr] = (d0 + 16 + rr > 0) ? 0.f : fmaxf(s10[rr], 0.f) * inv0;
                v01[rr] = (d0 - 16 + rr > 0) ? 0.f : fmaxf(s01[rr], 0.f) * inv1;
                v11[rr] = (d0 + rr > 0)      ? 0.f : fmaxf(s11[rr], 0.f) * inv1;
            }
            union { u32x4 u; bf16x8 h; } c0, c1;
            c0.u[0] = pk2(v00[0], v00[1]); c0.u[1] = pk2(v00[2], v00[3]);
            c0.u[2] = pk2(v10[0], v10[1]); c0.u[3] = pk2(v10[2], v10[3]);
            c1.u[0] = pk2(v01[0], v01[1]); c1.u[1] = pk2(v01[2], v01[3]);
            c1.u[2] = pk2(v11[0], v11[1]); c1.u[3] = pk2(v11[2], v11[3]);

            #pragma unroll
            for (int dt = 0; dt < 16; ++dt) {
                bf16x8 vv = *(const bf16x8*)&buf[cur][16 + dt][lane * 8];
                oacc0[dt] = mfma32(vv, c0.h, oacc0[dt]);
                oacc1[dt] = mfma32(vv, c1.h, oacc1[dt]);
            }
        }

        {
            const int j0g = (4 * g * (g + 1)) / 17;
            const int gslot = off + (j - j0g);
            u16* pb0 = part + ((((size_t)b * MAXOFF + gslot) * 16 + 2 * w) * 16) * 256 + lane * 4;
            u16* pb1 = pb0 + 16 * 256;
            #pragma unroll
            for (int dt = 0; dt < 16; ++dt) {
                bf16x4 t0v, t1v;
                t0v[0] = (short)f2b(oacc0[dt][0]); t0v[1] = (short)f2b(oacc0[dt][1]);
                t0v[2] = (short)f2b(oacc0[dt][2]); t0v[3] = (short)f2b(oacc0[dt][3]);
                t1v[0] = (short)f2b(oacc1[dt][0]); t1v[1] = (short)f2b(oacc1[dt][1]);
                t1v[2] = (short)f2b(oacc1[dt][2]); t1v[3] = (short)f2b(oacc1[dt][3]);
                *(bf16x4*)(pb0 + dt * 256) = t0v;
                *(bf16x4*)(pb1 + dt * 256) = t1v;
            }
            off += ((4 * (g + 1) * (g + 2) - 1) / 17) - j0g + 1;
        }
        ++g;
        kt = 0;
    }
}

// ---------------------------------------------------------------------------
// Kernel 3: fused reduce + output projection (1024 blocks x 256 thr).
// Round 28: batch-rotated group decode g = ((gb>>4) + 4b) & 15 balances
// per-CU Phase-A slot totals (4..32 -> 18..22) under round-robin dispatch.
// ---------------------------------------------------------------------------
__global__ __launch_bounds__(256, 4) void oproj_kernel(
    const u16* __restrict__ part, const u16* __restrict__ wo16,
    float* __restrict__ out)
{
    __shared__ u16 cb[16 * 256];   // 8 KB

    const int w = threadIdx.x >> 6, lane = threadIdx.x & 63;
    const int q4 = lane >> 4, ln = lane & 15;
    const int g16 = blockIdx.x;        // 0..1023
    const int b = g16 >> 8, gb = g16 & 255;
    const int g = ((gb >> 4) + 4 * b) & 15;   // 256-query group, batch-rotated
    const int tloc = gb & 15;

    int off = 0;
    for (int g2 = 0; g2 < g; ++g2) {
        const int j0 = (4 * g2 * (g2 + 1)) / 17;
        const int jl = (4 * (g2 + 1) * (g2 + 2) - 1) / 17;
        off += jl - j0 + 1;
    }
    const int j0g = (4 * g * (g + 1)) / 17;
    const int jlg = (4 * (g + 1) * (g + 2) - 1) / 17;
    const int nsl = jlg - j0g + 1;

    // Phase A: 16 chunks; wave w handles 4
    #pragma unroll
    for (int c4 = 0; c4 < 4; ++c4) {
        const int dt = w * 4 + c4;
        f32x4 s = f32x4{0.f, 0.f, 0.f, 0.f};
        for (int sl = 0; sl < nsl; ++sl) {
            const u16* p = part + ((((size_t)b * MAXOFF + off + sl) * 16 + tloc) * 16 + dt) * 256 + lane * 4;
            bf16x4 pv = *(const bf16x4*)p;
            s[0] += b2f(pv[0]); s[1] += b2f(pv[1]);
            s[2] += b2f(pv[2]); s[3] += b2f(pv[3]);
        }
        bf16x4 t;
        t[0] = (short)f2b(s[0]); t[1] = (short)f2b(s[1]);
        t[2] = (short)f2b(s[2]); t[3] = (short)f2b(s[3]);
        *(bf16x4*)&cb[dt * 256 + lane * 4] = t;
    }
    __syncthreads();

    // Phase B: wave w -> d-tiles [w*4, w*4+4)
    #pragma unroll
    for (int c4 = 0; c4 < 4; ++c4) {
        const int ct = w * 4 + c4;
        f32x4 acc = f32x4{0.f, 0.f, 0.f, 0.f};
        #pragma unroll
        for (int dt = 0; dt < 16; ++dt) {
            bf16x4 A = *(const bf16x4*)(wo16 + (size_t)(ct * 16 + dt) * 256 + lane * 4);
            bf16x4 B = *(const bf16x4*)&cb[dt * 256 + lane * 4];
            acc = mfma16(A, B, acc);
        }
        float* o = out + (size_t)((b * 16 + g) * 16 + tloc) * 16 * DD + (size_t)ln * DD + ct * 16 + q4 * 4;
        *(f32x4*)o = acc;
    }
}

extern "C" void kernel_launch(void* const* d_in, const int* in_sizes, int n_in,
                              void* d_out, int out_size, void* d_ws, size_t ws_size,
                              hipStream_t stream)
{
    const float* x  = (const float*)d_in[0];
    const float* Wq = (const float*)d_in[1];
    const float* Wk = (const float*)d_in[2];
    const float* Wv = (const float*)d_in[3];
    const float* Wo = (const float*)d_in[4];
    float* out = (float*)d_out;

    const size_t nW = (size_t)DD * DD;        // 65536
    const size_t nX = (size_t)BB * LL * DD;   // 4,194,304

    u16* wf   = (u16*)d_ws;                   // Wq,Wk,Wv B-frag order (384 KB)
    u16* wo16 = wf + 3 * nW;                  // Wo K=16 A-frag order (128 KB)
    u16* qfr  = wf + 4 * nW;                  // 8 MB
    u16* kfr  = qfr + nX;                     // 8 MB
    u16* vfr  = kfr + nX;                     // 8 MB
    u16* part = vfr + nX;                     // 41.9 MB (4 x 80 x 128 KB)

    wconv_kernel<<<dim3(128), dim3(256), 0, stream>>>(Wq, Wk, Wv, Wo, wf, wo16);
    qkv_kernel<<<dim3(1024), dim3(256), 0, stream>>>(x, wf, qfr, kfr, vfr);
    attn_kernel<<<dim3(256), dim3(512), 0, stream>>>(qfr, kfr, vfr, part);
    oproj_kernel<<<dim3(1024), dim3(256), 0, stream>>>(part, wo16, out);
}

// Round 17
// 149.204 us; speedup vs baseline: 1.1081x; 1.0106x over previous
//
#include <hip/hip_runtime.h>

#define BB 4
#define LL 4096
#define DD 256
#define MAXOFF 80    // max per-batch partial slots (exact bound: 78), slot = 256q x 256d

typedef short bf16x8 __attribute__((ext_vector_type(8)));
typedef short bf16x4 __attribute__((ext_vector_type(4)));
typedef float f32x4 __attribute__((ext_vector_type(4)));
typedef unsigned u32x4 __attribute__((ext_vector_type(4)));
typedef unsigned short u16;

__device__ inline u16 f2b(float f) {
    union { float f; unsigned u; } v; v.f = f;
    unsigned r = (v.u + 0x7fffu + ((v.u >> 16) & 1u)) >> 16;  // RNE
    return (u16)r;
}
__device__ inline float b2f(short s) {
    union { unsigned u; float f; } v; v.u = ((unsigned)(unsigned short)s) << 16;
    return v.f;
}
// pack 2 fp32 -> 2 bf16 (TRUNCATE) in one v_perm_b32
__device__ inline unsigned pk2(float lo, float hi) {
    union { float f; unsigned u; } a, b; a.f = lo; b.f = hi;
    return __builtin_amdgcn_perm(b.u, a.u, 0x07060302u);
}

__device__ inline f32x4 mfma32(bf16x8 a, bf16x8 b, f32x4 c) {
    return __builtin_amdgcn_mfma_f32_16x16x32_bf16(a, b, c, 0, 0, 0);
}
__device__ inline f32x4 mfma16(bf16x4 a, bf16x4 b, f32x4 c) {
    return __builtin_amdgcn_mfma_f32_16x16x16bf16_1k(a, b, c, 0, 0, 0);
}

__device__ inline void gl_lds(const u16* g, u16* l) {
    __builtin_amdgcn_global_load_lds(
        (const __attribute__((address_space(1))) void*)g,
        (__attribute__((address_space(3))) void*)l, 16, 0, 0);
}

// ===========================================================================
// Round 29: oproj load-balance refinement. Round-28's batch-rotation
// (-3.1us, 153.9->150.8, NEW BEST) confirmed the CU-imbalance mechanism:
// co-resident blocks {c,c+256,c+512,c+768} share gb -> per-CU Phase-A slot
// sums were 4..32; rotation flattened to {18,18,22,21}. This round uses
// independent per-batch permutations sigma_b(i): b0=i, b1=15-i, b2=(i+8)&15,
// b3=(7-i)&15 -> every CU class sums to exactly 19 or 20 (ideal 19.75);
// max 22 -> 20. Each sigma_b is a bijection: every (b,g,tloc) computed once.
// attn/qkv/wconv byte-identical to the 150.8us source.
// ===========================================================================

__global__ __launch_bounds__(256) void wconv_kernel(
    const float* __restrict__ Wq, const float* __restrict__ Wk,
    const float* __restrict__ Wv, const float* __restrict__ Wo,
    u16* __restrict__ wf, u16* __restrict__ wo16)
{
    const int w = threadIdx.x >> 6, lane = threadIdx.x & 63;
    const int q4 = lane >> 4, ln = lane & 15;
    const int id = blockIdx.x * 4 + w;          // 0..511
    const int mat = id >> 7, rem = id & 127, ct = rem >> 3, ks = rem & 7;
    if (mat < 3) {
        const float* W = (mat == 0) ? Wq : (mat == 1) ? Wk : Wv;
        const float* src = W + (size_t)(ct * 16 + ln) * DD + ks * 32 + q4 * 8;
        float4 f0 = ((const float4*)src)[0], f1 = ((const float4*)src)[1];
        bf16x8 t;
        t[0] = (short)f2b(f0.x); t[1] = (short)f2b(f0.y);
        t[2] = (short)f2b(f0.z); t[3] = (short)f2b(f0.w);
        t[4] = (short)f2b(f1.x); t[5] = (short)f2b(f1.y);
        t[6] = (short)f2b(f1.z); t[7] = (short)f2b(f1.w);
        *(bf16x8*)(wf + (size_t)mat * 65536 + (ct * 8 + ks) * 512 + lane * 8) = t;
    } else {
        const float* src = Wo + (size_t)(ct * 16 + ln) * DD + ks * 32 + q4 * 4;
        float4 f0 = *(const float4*)src;
        float4 f1 = *(const float4*)(src + 16);
        bf16x4 t0, t1;
        t0[0] = (short)f2b(f0.x); t0[1] = (short)f2b(f0.y);
        t0[2] = (short)f2b(f0.z); t0[3] = (short)f2b(f0.w);
        t1[0] = (short)f2b(f1.x); t1[1] = (short)f2b(f1.y);
        t1[2] = (short)f2b(f1.z); t1[3] = (short)f2b(f1.w);
        *(bf16x4*)(wo16 + (size_t)(ct * 16 + 2 * ks) * 256 + lane * 4) = t0;
        *(bf16x4*)(wo16 + (size_t)(ct * 16 + 2 * ks + 1) * 256 + lane * 4) = t1;
    }
}

// ---------------------------------------------------------------------------
// Kernel 1: QKV projection (1024 blocks x 256 thr, 4/CU).
// ---------------------------------------------------------------------------
__global__ __launch_bounds__(256, 4) void qkv_kernel(
    const float* __restrict__ x, const u16* __restrict__ wf,
    u16* __restrict__ qf, u16* __restrict__ kf_, u16* __restrict__ vf_)
{
    __shared__ u16 lt_q[32 * 136];   // [token 32][dim_local 128 +pad]
    __shared__ u16 lt_k[32 * 136];
    __shared__ u16 lt_v[128 * 40];   // [dim_local 128][token 32 +pad]

    const int w = threadIdx.x >> 6, lane = threadIdx.x & 63;
    const int q4 = lane >> 4, ln = lane & 15;
    const int tg = blockIdx.x >> 1, half = blockIdx.x & 1;
    const int tl = w & 1, dq = w >> 1;

    // A-frags: 16 token rows (fp32 -> bf16)
    bf16x8 a[8];
    {
        const float* xrow = x + (size_t)(tg * 32 + tl * 16 + ln) * DD;
        #pragma unroll
        for (int ks = 0; ks < 8; ++ks) {
            const float4* p = (const float4*)(xrow + ks * 32 + q4 * 8);
            float4 f0 = p[0], f1 = p[1];
            bf16x8 t;
            t[0] = (short)f2b(f0.x); t[1] = (short)f2b(f0.y);
            t[2] = (short)f2b(f0.z); t[3] = (short)f2b(f0.w);
            t[4] = (short)f2b(f1.x); t[5] = (short)f2b(f1.y);
            t[6] = (short)f2b(f1.z); t[7] = (short)f2b(f1.w);
            a[ks] = t;
        }
    }

    f32x4 acc0[4], acc1[4], acc2[4];
    #pragma unroll
    for (int cl = 0; cl < 4; ++cl) {
        acc0[cl] = f32x4{0.f, 0.f, 0.f, 0.f};
        acc1[cl] = f32x4{0.f, 0.f, 0.f, 0.f};
        acc2[cl] = f32x4{0.f, 0.f, 0.f, 0.f};
    }

    #pragma unroll
    for (int ks = 0; ks < 8; ++ks) {
        #pragma unroll
        for (int cl = 0; cl < 4; ++cl) {
            const int ct = half * 8 + dq * 4 + cl;
            const size_t off = ((size_t)ct * 8 + ks) * 512 + lane * 8;
            bf16x8 b0 = *(const bf16x8*)(wf + off);
            bf16x8 b1 = *(const bf16x8*)(wf + 65536 + off);
            bf16x8 b2 = *(const bf16x8*)(wf + 131072 + off);
            acc0[cl] = mfma32(a[ks], b0, acc0[cl]);
            acc1[cl] = mfma32(a[ks], b1, acc1[cl]);
            acc2[cl] = mfma32(a[ks], b2, acc2[cl]);
        }
    }

    // C-layout -> LDS (disjoint regions; single barrier after)
    #pragma unroll
    for (int cl = 0; cl < 4; ++cl) {
        const int coll = (dq * 4 + cl) * 16 + ln;   // local dim [0,128)
        #pragma unroll
        for (int r = 0; r < 4; ++r) {
            const int tok = tl * 16 + q4 * 4 + r;   // local token [0,32)
            lt_q[tok * 136 + coll] = f2b(acc0[cl][r]);
            lt_k[tok * 136 + coll] = f2b(acc1[cl][r]);
            lt_v[coll * 40 + tok] = f2b(acc2[cl][r]);
        }
    }
    __syncthreads();

    // Q/K: wave w -> h = w&1, ksl in {2*dq, 2*dq+1}
    {
        const int h = w & 1;
        #pragma unroll
        for (int e = 0; e < 2; ++e) {
            const int ksl = 2 * dq + e;             // local K-chunk [0,4)
            const int ks = half * 4 + ksl;          // global K-chunk [0,8)
            bf16x8 aq = *(const bf16x8*)&lt_q[(h * 16 + ln) * 136 + ksl * 32 + q4 * 8];
            bf16x8 ak = *(const bf16x8*)&lt_k[(h * 16 + ln) * 136 + ksl * 32 + q4 * 8];
            const size_t dst = (size_t)((tg * 2 + h) * 8 + ks) * 512 + lane * 8;
            *(bf16x8*)(qf + dst) = aq;
            *(bf16x8*)(kf_ + dst) = ak;
        }
    }
    // V: wave w -> dt_l in {2w, 2w+1}
    #pragma unroll
    for (int e = 0; e < 2; ++e) {
        const int dt_l = 2 * w + e;                 // local d-tile [0,8)
        bf16x4 lo = *(const bf16x4*)&lt_v[(dt_l * 16 + ln) * 40 + q4 * 4];
        bf16x4 hi = *(const bf16x4*)&lt_v[(dt_l * 16 + ln) * 40 + 16 + q4 * 4];
        bf16x8 t;
        t[0] = lo[0]; t[1] = lo[1]; t[2] = lo[2]; t[3] = lo[3];
        t[4] = hi[0]; t[5] = hi[1]; t[6] = hi[2]; t[7] = hi[3];
        *(bf16x8*)(vf_ + (size_t)(tg * 16 + half * 8 + dt_l) * 512 + lane * 8) = t;
    }
}

// ---------------------------------------------------------------------------
// Kernel 2: causal ReLU attention. 256-query groups, 8 waves x 32 queries,
// 256 blocks x 512 threads, 64KB LDS dbuf, 17 u-steps/block, XCD decode.
// ---------------------------------------------------------------------------
__global__ __launch_bounds__(512, 2) void attn_kernel(
    const u16* __restrict__ qf, const u16* __restrict__ kfr,
    const u16* __restrict__ vfr, u16* __restrict__ part)
{
    __shared__ u16 buf[2][32][512];   // 64 KB: K (chunks 0-15) + V (16-31), dbuf

    const int id = blockIdx.x;                  // 0..255
    const int xcd = id & 7;
    const int b = xcd >> 1;                     // 2 XCDs per batch
    const int j = ((xcd & 1) << 5) | (id >> 3); // segment 0..63

    const int w = threadIdx.x >> 6, lane = threadIdx.x & 63;
    const int q4 = lane >> 4, ln = lane & 15;

    const int u0 = 17 * j;
    const int u1 = u0 + 17;

    int g = (int)((sqrtf((float)u0 + 1.0f) - 1.0f) * 0.5f);
    while (4 * (g + 1) * (g + 2) <= u0) ++g;
    while (4 * g * (g + 1) > u0) --g;
    int kt = u0 - 4 * g * (g + 1);
    int u = u0;

    int off = 0;
    for (int g2 = 0; g2 < g; ++g2) {
        const int j0 = (4 * g2 * (g2 + 1)) / 17;
        const int jl = (4 * (g2 + 1) * (g2 + 2) - 1) / 17;
        off += jl - j0 + 1;
    }

    // prologue: K+V tile u0 (32 chunks over 8 waves)
    {
        const size_t cb = (size_t)((b * 128 + kt) * 16) * 512;
        #pragma unroll
        for (int c4 = 0; c4 < 4; ++c4) {
            const int c = w * 4 + c4;
            const u16* gsrc = ((c < 16) ? (kfr + cb + c * 512)
                                        : (vfr + cb + (c - 16) * 512)) + lane * 8;
            gl_lds(gsrc, &buf[u0 & 1][c][0]);
        }
    }

    while (u < u1) {
        const int ktend = 8 * g + 8;
        const int rem = u1 - u;
        const int kt_stop = (ktend < kt + rem) ? ktend : (kt + rem);
        const int t0 = g * 16 + 2 * w;          // t-tile (16 q) index, 2 per wave
        const int qg0 = t0 * 16 + ln;
        const float inv0 = 1.0f / (float)(qg0 > 1 ? qg0 : 1);
        const float inv1 = 1.0f / (float)(qg0 + 16);

        bf16x8 qB0[8], qB1[8];
        {
            const u16* qb0 = qf + (size_t)(t0 * 8) * 512 + (size_t)b * (128 * 16 * 512) + lane * 8;
            #pragma unroll
            for (int ks = 0; ks < 8; ++ks) {
                qB0[ks] = *(const bf16x8*)(qb0 + ks * 512);
                qB1[ks] = *(const bf16x8*)(qb0 + (8 + ks) * 512);
            }
        }

        f32x4 oacc0[16], oacc1[16];
        #pragma unroll
        for (int dt = 0; dt < 16; ++dt) {
            oacc0[dt] = f32x4{0.f, 0.f, 0.f, 0.f};
            oacc1[dt] = f32x4{0.f, 0.f, 0.f, 0.f};
        }

        #pragma unroll 1
        for (; kt < kt_stop; ++kt, ++u) {
            const int cur = u & 1;
            __syncthreads();

            if (u + 1 < u1) {
                const int ktn = (kt + 1 < ktend) ? (kt + 1) : 0;
                const size_t cb = (size_t)((b * 128 + ktn) * 16) * 512;
                #pragma unroll
                for (int c4 = 0; c4 < 4; ++c4) {
                    const int c = w * 4 + c4;
                    const u16* gsrc = ((c < 16) ? (kfr + cb + c * 512)
                                                : (vfr + cb + (c - 16) * 512)) + lane * 8;
                    gl_lds(gsrc, &buf[cur ^ 1][c][0]);
                }
            }

            f32x4 s00 = f32x4{0.f, 0.f, 0.f, 0.f};
            f32x4 s10 = f32x4{0.f, 0.f, 0.f, 0.f};
            f32x4 s01 = f32x4{0.f, 0.f, 0.f, 0.f};
            f32x4 s11 = f32x4{0.f, 0.f, 0.f, 0.f};
            #pragma unroll
            for (int ks = 0; ks < 8; ++ks) {
                bf16x8 kf0 = *(const bf16x8*)&buf[cur][ks][lane * 8];
                bf16x8 kf1 = *(const bf16x8*)&buf[cur][8 + ks][lane * 8];
                s00 = mfma32(kf0, qB0[ks], s00);
                s10 = mfma32(kf1, qB0[ks], s10);
                s01 = mfma32(kf0, qB1[ks], s01);
                s11 = mfma32(kf1, qB1[ks], s11);
            }

            const int d0 = kt * 32 + q4 * 4 - qg0;
            float v00[4], v10[4], v01[4], v11[4];
            #pragma unroll
            for (int rr = 0; rr < 4; ++rr) {
                v00[rr] = (d0 + rr > 0)      ? 0.f : fmaxf(s00[rr], 0.f) * inv0;
                v10[rr] = (d0 + 16 + rr > 0) ? 0.f : fmaxf(s10[rr], 0.f) * inv0;
                v01[rr] = (d0 - 16 + rr > 0) ? 0.f : fmaxf(s01[rr], 0.f) * inv1;
                v11[rr] = (d0 + rr > 0)      ? 0.f : fmaxf(s11[rr], 0.f) * inv1;
            }
            union { u32x4 u; bf16x8 h; } c0, c1;
            c0.u[0] = pk2(v00[0], v00[1]); c0.u[1] = pk2(v00[2], v00[3]);
            c0.u[2] = pk2(v10[0], v10[1]); c0.u[3] = pk2(v10[2], v10[3]);
            c1.u[0] = pk2(v01[0], v01[1]); c1.u[1] = pk2(v01[2], v01[3]);
            c1.u[2] = pk2(v11[0], v11[1]); c1.u[3] = pk2(v11[2], v11[3]);

            #pragma unroll
            for (int dt = 0; dt < 16; ++dt) {
                bf16x8 vv = *(const bf16x8*)&buf[cur][16 + dt][lane * 8];
                oacc0[dt] = mfma32(vv, c0.h, oacc0[dt]);
                oacc1[dt] = mfma32(vv, c1.h, oacc1[dt]);
            }
        }

        {
            const int j0g = (4 * g * (g + 1)) / 17;
            const int gslot = off + (j - j0g);
            u16* pb0 = part + ((((size_t)b * MAXOFF + gslot) * 16 + 2 * w) * 16) * 256 + lane * 4;
            u16* pb1 = pb0 + 16 * 256;
            #pragma unroll
            for (int dt = 0; dt < 16; ++dt) {
                bf16x4 t0v, t1v;
                t0v[0] = (short)f2b(oacc0[dt][0]); t0v[1] = (short)f2b(oacc0[dt][1]);
                t0v[2] = (short)f2b(oacc0[dt][2]); t0v[3] = (short)f2b(oacc0[dt][3]);
                t1v[0] = (short)f2b(oacc1[dt][0]); t1v[1] = (short)f2b(oacc1[dt][1]);
                t1v[2] = (short)f2b(oacc1[dt][2]); t1v[3] = (short)f2b(oacc1[dt][3]);
                *(bf16x4*)(pb0 + dt * 256) = t0v;
                *(bf16x4*)(pb1 + dt * 256) = t1v;
            }
            off += ((4 * (g + 1) * (g + 2) - 1) / 17) - j0g + 1;
        }
        ++g;
        kt = 0;
    }
}

// ---------------------------------------------------------------------------
// Kernel 3: fused reduce + output projection (1024 blocks x 256 thr).
// Round 29: per-batch permutation decode sigma_b(i) flattens per-CU Phase-A
// slot sums to exactly {19,20} (was {18,18,22,21} with cyclic rotation).
// ---------------------------------------------------------------------------
__global__ __launch_bounds__(256, 4) void oproj_kernel(
    const u16* __restrict__ part, const u16* __restrict__ wo16,
    float* __restrict__ out)
{
    __shared__ u16 cb[16 * 256];   // 8 KB

    const int w = threadIdx.x >> 6, lane = threadIdx.x & 63;
    const int q4 = lane >> 4, ln = lane & 15;
    const int g16 = blockIdx.x;        // 0..1023
    const int b = g16 >> 8, gb = g16 & 255;
    const int i = gb >> 4;
    // sigma_b: b0 = i, b1 = 15-i, b2 = (i+8)&15, b3 = (7-i)&15
    int g = (b & 1) ? (15 - i) : i;
    if (b & 2) g = (g + 8) & 15;
    const int tloc = gb & 15;

    int off = 0;
    for (int g2 = 0; g2 < g; ++g2) {
        const int j0 = (4 * g2 * (g2 + 1)) / 17;
        const int jl = (4 * (g2 + 1) * (g2 + 2) - 1) / 17;
        off += jl - j0 + 1;
    }
    const int j0g = (4 * g * (g + 1)) / 17;
    const int jlg = (4 * (g + 1) * (g + 2) - 1) / 17;
    const int nsl = jlg - j0g + 1;

    // Phase A: 16 chunks; wave w handles 4
    #pragma unroll
    for (int c4 = 0; c4 < 4; ++c4) {
        const int dt = w * 4 + c4;
        f32x4 s = f32x4{0.f, 0.f, 0.f, 0.f};
        for (int sl = 0; sl < nsl; ++sl) {
            const u16* p = part + ((((size_t)b * MAXOFF + off + sl) * 16 + tloc) * 16 + dt) * 256 + lane * 4;
            bf16x4 pv = *(const bf16x4*)p;
            s[0] += b2f(pv[0]); s[1] += b2f(pv[1]);
            s[2] += b2f(pv[2]); s[3] += b2f(pv[3]);
        }
        bf16x4 t;
        t[0] = (short)f2b(s[0]); t[1] = (short)f2b(s[1]);
        t[2] = (short)f2b(s[2]); t[3] = (short)f2b(s[3]);
        *(bf16x4*)&cb[dt * 256 + lane * 4] = t;
    }
    __syncthreads();

    // Phase B: wave w -> d-tiles [w*4, w*4+4)
    #pragma unroll
    for (int c4 = 0; c4 < 4; ++c4) {
        const int ct = w * 4 + c4;
        f32x4 acc = f32x4{0.f, 0.f, 0.f, 0.f};
        #pragma unroll
        for (int dt = 0; dt < 16; ++dt) {
            bf16x4 A = *(const bf16x4*)(wo16 + (size_t)(ct * 16 + dt) * 256 + lane * 4);
            bf16x4 B = *(const bf16x4*)&cb[dt * 256 + lane * 4];
            acc = mfma16(A, B, acc);
        }
        float* o = out + (size_t)((b * 16 + g) * 16 + tloc) * 16 * DD + (size_t)ln * DD + ct * 16 + q4 * 4;
        *(f32x4*)o = acc;
    }
}

extern "C" void kernel_launch(void* const* d_in, const int* in_sizes, int n_in,
                              void* d_out, int out_size, void* d_ws, size_t ws_size,
                              hipStream_t stream)
{
    const float* x  = (const float*)d_in[0];
    const float* Wq = (const float*)d_in[1];
    const float* Wk = (const float*)d_in[2];
    const float* Wv = (const float*)d_in[3];
    const float* Wo = (const float*)d_in[4];
    float* out = (float*)d_out;

    const size_t nW = (size_t)DD * DD;        // 65536
    const size_t nX = (size_t)BB * LL * DD;   // 4,194,304

    u16* wf   = (u16*)d_ws;                   // Wq,Wk,Wv B-frag order (384 KB)
    u16* wo16 = wf + 3 * nW;                  // Wo K=16 A-frag order (128 KB)
    u16* qfr  = wf + 4 * nW;                  // 8 MB
    u16* kfr  = qfr + nX;                     // 8 MB
    u16* vfr  = kfr + nX;                     // 8 MB
    u16* part = vfr + nX;                     // 41.9 MB (4 x 80 x 128 KB)

    wconv_kernel<<<dim3(128), dim3(256), 0, stream>>>(Wq, Wk, Wv, Wo, wf, wo16);
    qkv_kernel<<<dim3(1024), dim3(256), 0, stream>>>(x, wf, qfr, kfr, vfr);
    attn_kernel<<<dim3(256), dim3(512), 0, stream>>>(qfr, kfr, vfr, part);
    oproj_kernel<<<dim3(1024), dim3(256), 0, stream>>>(part, wo16, out);
}

// Round 18
// 148.988 us; speedup vs baseline: 1.1097x; 1.0015x over previous
//
#include <hip/hip_runtime.h>

#define BB 4
#define LL 4096
#define DD 256
#define MAXOFF 80    // max per-batch partial slots (exact bound: 78), slot = 256q x 256d

typedef short bf16x8 __attribute__((ext_vector_type(8)));
typedef short bf16x4 __attribute__((ext_vector_type(4)));
typedef float f32x4 __attribute__((ext_vector_type(4)));
typedef unsigned u32x4 __attribute__((ext_vector_type(4)));
typedef unsigned short u16;

__device__ inline u16 f2b(float f) {
    union { float f; unsigned u; } v; v.f = f;
    unsigned r = (v.u + 0x7fffu + ((v.u >> 16) & 1u)) >> 16;  // RNE
    return (u16)r;
}
__device__ inline float b2f(short s) {
    union { unsigned u; float f; } v; v.u = ((unsigned)(unsigned short)s) << 16;
    return v.f;
}
// pack 2 fp32 -> 2 bf16 (TRUNCATE) in one v_perm_b32
__device__ inline unsigned pk2(float lo, float hi) {
    union { float f; unsigned u; } a, b; a.f = lo; b.f = hi;
    return __builtin_amdgcn_perm(b.u, a.u, 0x07060302u);
}

__device__ inline f32x4 mfma32(bf16x8 a, bf16x8 b, f32x4 c) {
    return __builtin_amdgcn_mfma_f32_16x16x32_bf16(a, b, c, 0, 0, 0);
}
__device__ inline f32x4 mfma16(bf16x4 a, bf16x4 b, f32x4 c) {
    return __builtin_amdgcn_mfma_f32_16x16x16bf16_1k(a, b, c, 0, 0, 0);
}

__device__ inline void gl_lds(const u16* g, u16* l) {
    __builtin_amdgcn_global_load_lds(
        (const __attribute__((address_space(1))) void*)g,
        (__attribute__((address_space(3))) void*)l, 16, 0, 0);
}

// ===========================================================================
// FINAL (round 30 = round-29 source, reproduction/lock-in). Measured 149.2us
// (session best; baseline band was 152.9-154.8 before the oproj balance
// work). Two-win mechanism: oproj per-CU load balance under round-robin
// dispatch -- co-resident blocks {c,c+256,c+512,c+768} share gb, so the
// group decode uses per-batch bijections sigma_b(i): b0=i, b1=15-i,
// b2=(i+8)&15, b3=(7-i)&15, flattening per-CU Phase-A slot sums from 4..32
// (original) -> {18,18,22,21} (rotation, -3.1us) -> {19,20} (this, -1.6us).
//
// Search summary (17 measured rounds, all alternatives falsified):
//   attn: dbuf+syncthreads 43.3 BEST | PV-pipeline 53 | 64q/wave@1wave 80 |
//         2 blk/CU 48 | KVBLK=64 44.2 | triple-buffer counted-vmcnt 55
//   qkv:  1024x256@4/CU BEST | 512x512@2/CU +11us | 3072x256@5/CU +10us
//   oproj: balanced decode BEST (-4.7us cumulative vs naive)
// Timed window ~149us = harness ws-poison fill ~44 + attn ~44 + qkv/oproj/
// wconv/gaps ~61. attn MfmaUtil ~27-31%/HBM ~19% is a structural plateau of
// the query-split LDS-broadcast decomposition at HIP source level
// (cf. m131-m141); beyond it lies producer-consumer wave specialization or
// an inline-asm K-loop, out of scope for this session.
// ===========================================================================

__global__ __launch_bounds__(256) void wconv_kernel(
    const float* __restrict__ Wq, const float* __restrict__ Wk,
    const float* __restrict__ Wv, const float* __restrict__ Wo,
    u16* __restrict__ wf, u16* __restrict__ wo16)
{
    const int w = threadIdx.x >> 6, lane = threadIdx.x & 63;
    const int q4 = lane >> 4, ln = lane & 15;
    const int id = blockIdx.x * 4 + w;          // 0..511
    const int mat = id >> 7, rem = id & 127, ct = rem >> 3, ks = rem & 7;
    if (mat < 3) {
        const float* W = (mat == 0) ? Wq : (mat == 1) ? Wk : Wv;
        const float* src = W + (size_t)(ct * 16 + ln) * DD + ks * 32 + q4 * 8;
        float4 f0 = ((const float4*)src)[0], f1 = ((const float4*)src)[1];
        bf16x8 t;
        t[0] = (short)f2b(f0.x); t[1] = (short)f2b(f0.y);
        t[2] = (short)f2b(f0.z); t[3] = (short)f2b(f0.w);
        t[4] = (short)f2b(f1.x); t[5] = (short)f2b(f1.y);
        t[6] = (short)f2b(f1.z); t[7] = (short)f2b(f1.w);
        *(bf16x8*)(wf + (size_t)mat * 65536 + (ct * 8 + ks) * 512 + lane * 8) = t;
    } else {
        const float* src = Wo + (size_t)(ct * 16 + ln) * DD + ks * 32 + q4 * 4;
        float4 f0 = *(const float4*)src;
        float4 f1 = *(const float4*)(src + 16);
        bf16x4 t0, t1;
        t0[0] = (short)f2b(f0.x); t0[1] = (short)f2b(f0.y);
        t0[2] = (short)f2b(f0.z); t0[3] = (short)f2b(f0.w);
        t1[0] = (short)f2b(f1.x); t1[1] = (short)f2b(f1.y);
        t1[2] = (short)f2b(f1.z); t1[3] = (short)f2b(f1.w);
        *(bf16x4*)(wo16 + (size_t)(ct * 16 + 2 * ks) * 256 + lane * 4) = t0;
        *(bf16x4*)(wo16 + (size_t)(ct * 16 + 2 * ks + 1) * 256 + lane * 4) = t1;
    }
}

// ---------------------------------------------------------------------------
// Kernel 1: QKV projection (1024 blocks x 256 thr, 4/CU).
// ---------------------------------------------------------------------------
__global__ __launch_bounds__(256, 4) void qkv_kernel(
    const float* __restrict__ x, const u16* __restrict__ wf,
    u16* __restrict__ qf, u16* __restrict__ kf_, u16* __restrict__ vf_)
{
    __shared__ u16 lt_q[32 * 136];   // [token 32][dim_local 128 +pad]
    __shared__ u16 lt_k[32 * 136];
    __shared__ u16 lt_v[128 * 40];   // [dim_local 128][token 32 +pad]

    const int w = threadIdx.x >> 6, lane = threadIdx.x & 63;
    const int q4 = lane >> 4, ln = lane & 15;
    const int tg = blockIdx.x >> 1, half = blockIdx.x & 1;
    const int tl = w & 1, dq = w >> 1;

    // A-frags: 16 token rows (fp32 -> bf16)
    bf16x8 a[8];
    {
        const float* xrow = x + (size_t)(tg * 32 + tl * 16 + ln) * DD;
        #pragma unroll
        for (int ks = 0; ks < 8; ++ks) {
            const float4* p = (const float4*)(xrow + ks * 32 + q4 * 8);
            float4 f0 = p[0], f1 = p[1];
            bf16x8 t;
            t[0] = (short)f2b(f0.x); t[1] = (short)f2b(f0.y);
            t[2] = (short)f2b(f0.z); t[3] = (short)f2b(f0.w);
            t[4] = (short)f2b(f1.x); t[5] = (short)f2b(f1.y);
            t[6] = (short)f2b(f1.z); t[7] = (short)f2b(f1.w);
            a[ks] = t;
        }
    }

    f32x4 acc0[4], acc1[4], acc2[4];
    #pragma unroll
    for (int cl = 0; cl < 4; ++cl) {
        acc0[cl] = f32x4{0.f, 0.f, 0.f, 0.f};
        acc1[cl] = f32x4{0.f, 0.f, 0.f, 0.f};
        acc2[cl] = f32x4{0.f, 0.f, 0.f, 0.f};
    }

    #pragma unroll
    for (int ks = 0; ks < 8; ++ks) {
        #pragma unroll
        for (int cl = 0; cl < 4; ++cl) {
            const int ct = half * 8 + dq * 4 + cl;
            const size_t off = ((size_t)ct * 8 + ks) * 512 + lane * 8;
            bf16x8 b0 = *(const bf16x8*)(wf + off);
            bf16x8 b1 = *(const bf16x8*)(wf + 65536 + off);
            bf16x8 b2 = *(const bf16x8*)(wf + 131072 + off);
            acc0[cl] = mfma32(a[ks], b0, acc0[cl]);
            acc1[cl] = mfma32(a[ks], b1, acc1[cl]);
            acc2[cl] = mfma32(a[ks], b2, acc2[cl]);
        }
    }

    // C-layout -> LDS (disjoint regions; single barrier after)
    #pragma unroll
    for (int cl = 0; cl < 4; ++cl) {
        const int coll = (dq * 4 + cl) * 16 + ln;   // local dim [0,128)
        #pragma unroll
        for (int r = 0; r < 4; ++r) {
            const int tok = tl * 16 + q4 * 4 + r;   // local token [0,32)
            lt_q[tok * 136 + coll] = f2b(acc0[cl][r]);
            lt_k[tok * 136 + coll] = f2b(acc1[cl][r]);
            lt_v[coll * 40 + tok] = f2b(acc2[cl][r]);
        }
    }
    __syncthreads();

    // Q/K: wave w -> h = w&1, ksl in {2*dq, 2*dq+1}
    {
        const int h = w & 1;
        #pragma unroll
        for (int e = 0; e < 2; ++e) {
            const int ksl = 2 * dq + e;             // local K-chunk [0,4)
            const int ks = half * 4 + ksl;          // global K-chunk [0,8)
            bf16x8 aq = *(const bf16x8*)&lt_q[(h * 16 + ln) * 136 + ksl * 32 + q4 * 8];
            bf16x8 ak = *(const bf16x8*)&lt_k[(h * 16 + ln) * 136 + ksl * 32 + q4 * 8];
            const size_t dst = (size_t)((tg * 2 + h) * 8 + ks) * 512 + lane * 8;
            *(bf16x8*)(qf + dst) = aq;
            *(bf16x8*)(kf_ + dst) = ak;
        }
    }
    // V: wave w -> dt_l in {2w, 2w+1}
    #pragma unroll
    for (int e = 0; e < 2; ++e) {
        const int dt_l = 2 * w + e;                 // local d-tile [0,8)
        bf16x4 lo = *(const bf16x4*)&lt_v[(dt_l * 16 + ln) * 40 + q4 * 4];
        bf16x4 hi = *(const bf16x4*)&lt_v[(dt_l * 16 + ln) * 40 + 16 + q4 * 4];
        bf16x8 t;
        t[0] = lo[0]; t[1] = lo[1]; t[2] = lo[2]; t[3] = lo[3];
        t[4] = hi[0]; t[5] = hi[1]; t[6] = hi[2]; t[7] = hi[3];
        *(bf16x8*)(vf_ + (size_t)(tg * 16 + half * 8 + dt_l) * 512 + lane * 8) = t;
    }
}

// ---------------------------------------------------------------------------
// Kernel 2: causal ReLU attention. 256-query groups, 8 waves x 32 queries,
// 256 blocks x 512 threads, 64KB LDS dbuf, 17 u-steps/block, XCD decode.
// ---------------------------------------------------------------------------
__global__ __launch_bounds__(512, 2) void attn_kernel(
    const u16* __restrict__ qf, const u16* __restrict__ kfr,
    const u16* __restrict__ vfr, u16* __restrict__ part)
{
    __shared__ u16 buf[2][32][512];   // 64 KB: K (chunks 0-15) + V (16-31), dbuf

    const int id = blockIdx.x;                  // 0..255
    const int xcd = id & 7;
    const int b = xcd >> 1;                     // 2 XCDs per batch
    const int j = ((xcd & 1) << 5) | (id >> 3); // segment 0..63

    const int w = threadIdx.x >> 6, lane = threadIdx.x & 63;
    const int q4 = lane >> 4, ln = lane & 15;

    const int u0 = 17 * j;
    const int u1 = u0 + 17;

    int g = (int)((sqrtf((float)u0 + 1.0f) - 1.0f) * 0.5f);
    while (4 * (g + 1) * (g + 2) <= u0) ++g;
    while (4 * g * (g + 1) > u0) --g;
    int kt = u0 - 4 * g * (g + 1);
    int u = u0;

    int off = 0;
    for (int g2 = 0; g2 < g; ++g2) {
        const int j0 = (4 * g2 * (g2 + 1)) / 17;
        const int jl = (4 * (g2 + 1) * (g2 + 2) - 1) / 17;
        off += jl - j0 + 1;
    }

    // prologue: K+V tile u0 (32 chunks over 8 waves)
    {
        const size_t cb = (size_t)((b * 128 + kt) * 16) * 512;
        #pragma unroll
        for (int c4 = 0; c4 < 4; ++c4) {
            const int c = w * 4 + c4;
            const u16* gsrc = ((c < 16) ? (kfr + cb + c * 512)
                                        : (vfr + cb + (c - 16) * 512)) + lane * 8;
            gl_lds(gsrc, &buf[u0 & 1][c][0]);
        }
    }

    while (u < u1) {
        const int ktend = 8 * g + 8;
        const int rem = u1 - u;
        const int kt_stop = (ktend < kt + rem) ? ktend : (kt + rem);
        const int t0 = g * 16 + 2 * w;          // t-tile (16 q) index, 2 per wave
        const int qg0 = t0 * 16 + ln;
        const float inv0 = 1.0f / (float)(qg0 > 1 ? qg0 : 1);
        const float inv1 = 1.0f / (float)(qg0 + 16);

        bf16x8 qB0[8], qB1[8];
        {
            const u16* qb0 = qf + (size_t)(t0 * 8) * 512 + (size_t)b * (128 * 16 * 512) + lane * 8;
            #pragma unroll
            for (int ks = 0; ks < 8; ++ks) {
                qB0[ks] = *(const bf16x8*)(qb0 + ks * 512);
                qB1[ks] = *(const bf16x8*)(qb0 + (8 + ks) * 512);
            }
        }

        f32x4 oacc0[16], oacc1[16];
        #pragma unroll
        for (int dt = 0; dt < 16; ++dt) {
            oacc0[dt] = f32x4{0.f, 0.f, 0.f, 0.f};
            oacc1[dt] = f32x4{0.f, 0.f, 0.f, 0.f};
        }

        #pragma unroll 1
        for (; kt < kt_stop; ++kt, ++u) {
            const int cur = u & 1;
            __syncthreads();

            if (u + 1 < u1) {
                const int ktn = (kt + 1 < ktend) ? (kt + 1) : 0;
                const size_t cb = (size_t)((b * 128 + ktn) * 16) * 512;
                #pragma unroll
                for (int c4 = 0; c4 < 4; ++c4) {
                    const int c = w * 4 + c4;
                    const u16* gsrc = ((c < 16) ? (kfr + cb + c * 512)
                                                : (vfr + cb + (c - 16) * 512)) + lane * 8;
                    gl_lds(gsrc, &buf[cur ^ 1][c][0]);
                }
            }

            f32x4 s00 = f32x4{0.f, 0.f, 0.f, 0.f};
            f32x4 s10 = f32x4{0.f, 0.f, 0.f, 0.f};
            f32x4 s01 = f32x4{0.f, 0.f, 0.f, 0.f};
            f32x4 s11 = f32x4{0.f, 0.f, 0.f, 0.f};
            #pragma unroll
            for (int ks = 0; ks < 8; ++ks) {
                bf16x8 kf0 = *(const bf16x8*)&buf[cur][ks][lane * 8];
                bf16x8 kf1 = *(const bf16x8*)&buf[cur][8 + ks][lane * 8];
                s00 = mfma32(kf0, qB0[ks], s00);
                s10 = mfma32(kf1, qB0[ks], s10);
                s01 = mfma32(kf0, qB1[ks], s01);
                s11 = mfma32(kf1, qB1[ks], s11);
            }

            const int d0 = kt * 32 + q4 * 4 - qg0;
            float v00[4], v10[4], v01[4], v11[4];
            #pragma unroll
            for (int rr = 0; rr < 4; ++rr) {
                v00[rr] = (d0 + rr > 0)      ? 0.f : fmaxf(s00[rr], 0.f) * inv0;
                v10[rr] = (d0 + 16 + rr > 0) ? 0.f : fmaxf(s10[rr], 0.f) * inv0;
                v01[rr] = (d0 - 16 + rr > 0) ? 0.f : fmaxf(s01[rr], 0.f) * inv1;
                v11[rr] = (d0 + rr > 0)      ? 0.f : fmaxf(s11[rr], 0.f) * inv1;
            }
            union { u32x4 u; bf16x8 h; } c0, c1;
            c0.u[0] = pk2(v00[0], v00[1]); c0.u[1] = pk2(v00[2], v00[3]);
            c0.u[2] = pk2(v10[0], v10[1]); c0.u[3] = pk2(v10[2], v10[3]);
            c1.u[0] = pk2(v01[0], v01[1]); c1.u[1] = pk2(v01[2], v01[3]);
            c1.u[2] = pk2(v11[0], v11[1]); c1.u[3] = pk2(v11[2], v11[3]);

            #pragma unroll
            for (int dt = 0; dt < 16; ++dt) {
                bf16x8 vv = *(const bf16x8*)&buf[cur][16 + dt][lane * 8];
                oacc0[dt] = mfma32(vv, c0.h, oacc0[dt]);
                oacc1[dt] = mfma32(vv, c1.h, oacc1[dt]);
            }
        }

        {
            const int j0g = (4 * g * (g + 1)) / 17;
            const int gslot = off + (j - j0g);
            u16* pb0 = part + ((((size_t)b * MAXOFF + gslot) * 16 + 2 * w) * 16) * 256 + lane * 4;
            u16* pb1 = pb0 + 16 * 256;
            #pragma unroll
            for (int dt = 0; dt < 16; ++dt) {
                bf16x4 t0v, t1v;
                t0v[0] = (short)f2b(oacc0[dt][0]); t0v[1] = (short)f2b(oacc0[dt][1]);
                t0v[2] = (short)f2b(oacc0[dt][2]); t0v[3] = (short)f2b(oacc0[dt][3]);
                t1v[0] = (short)f2b(oacc1[dt][0]); t1v[1] = (short)f2b(oacc1[dt][1]);
                t1v[2] = (short)f2b(oacc1[dt][2]); t1v[3] = (short)f2b(oacc1[dt][3]);
                *(bf16x4*)(pb0 + dt * 256) = t0v;
                *(bf16x4*)(pb1 + dt * 256) = t1v;
            }
            off += ((4 * (g + 1) * (g + 2) - 1) / 17) - j0g + 1;
        }
        ++g;
        kt = 0;
    }
}

// ---------------------------------------------------------------------------
// Kernel 3: fused reduce + output projection (1024 blocks x 256 thr).
// Per-batch permutation decode sigma_b(i) flattens per-CU Phase-A slot
// sums to exactly {19,20} (ideal 19.75) under round-robin dispatch.
// ---------------------------------------------------------------------------
__global__ __launch_bounds__(256, 4) void oproj_kernel(
    const u16* __restrict__ part, const u16* __restrict__ wo16,
    float* __restrict__ out)
{
    __shared__ u16 cb[16 * 256];   // 8 KB

    const int w = threadIdx.x >> 6, lane = threadIdx.x & 63;
    const int q4 = lane >> 4, ln = lane & 15;
    const int g16 = blockIdx.x;        // 0..1023
    const int b = g16 >> 8, gb = g16 & 255;
    const int i = gb >> 4;
    // sigma_b: b0 = i, b1 = 15-i, b2 = (i+8)&15, b3 = (7-i)&15
    int g = (b & 1) ? (15 - i) : i;
    if (b & 2) g = (g + 8) & 15;
    const int tloc = gb & 15;

    int off = 0;
    for (int g2 = 0; g2 < g; ++g2) {
        const int j0 = (4 * g2 * (g2 + 1)) / 17;
        const int jl = (4 * (g2 + 1) * (g2 + 2) - 1) / 17;
        off += jl - j0 + 1;
    }
    const int j0g = (4 * g * (g + 1)) / 17;
    const int jlg = (4 * (g + 1) * (g + 2) - 1) / 17;
    const int nsl = jlg - j0g + 1;

    // Phase A: 16 chunks; wave w handles 4
    #pragma unroll
    for (int c4 = 0; c4 < 4; ++c4) {
        const int dt = w * 4 + c4;
        f32x4 s = f32x4{0.f, 0.f, 0.f, 0.f};
        for (int sl = 0; sl < nsl; ++sl) {
            const u16* p = part + ((((size_t)b * MAXOFF + off + sl) * 16 + tloc) * 16 + dt) * 256 + lane * 4;
            bf16x4 pv = *(const bf16x4*)p;
            s[0] += b2f(pv[0]); s[1] += b2f(pv[1]);
            s[2] += b2f(pv[2]); s[3] += b2f(pv[3]);
        }
        bf16x4 t;
        t[0] = (short)f2b(s[0]); t[1] = (short)f2b(s[1]);
        t[2] = (short)f2b(s[2]); t[3] = (short)f2b(s[3]);
        *(bf16x4*)&cb[dt * 256 + lane * 4] = t;
    }
    __syncthreads();

    // Phase B: wave w -> d-tiles [w*4, w*4+4)
    #pragma unroll
    for (int c4 = 0; c4 < 4; ++c4) {
        const int ct = w * 4 + c4;
        f32x4 acc = f32x4{0.f, 0.f, 0.f, 0.f};
        #pragma unroll
        for (int dt = 0; dt < 16; ++dt) {
            bf16x4 A = *(const bf16x4*)(wo16 + (size_t)(ct * 16 + dt) * 256 + lane * 4);
            bf16x4 B = *(const bf16x4*)&cb[dt * 256 + lane * 4];
            acc = mfma16(A, B, acc);
        }
        float* o = out + (size_t)((b * 16 + g) * 16 + tloc) * 16 * DD + (size_t)ln * DD + ct * 16 + q4 * 4;
        *(f32x4*)o = acc;
    }
}

extern "C" void kernel_launch(void* const* d_in, const int* in_sizes, int n_in,
                              void* d_out, int out_size, void* d_ws, size_t ws_size,
                              hipStream_t stream)
{
    const float* x  = (const float*)d_in[0];
    const float* Wq = (const float*)d_in[1];
    const float* Wk = (const float*)d_in[2];
    const float* Wv = (const float*)d_in[3];
    const float* Wo = (const float*)d_in[4];
    float* out = (float*)d_out;

    const size_t nW = (size_t)DD * DD;        // 65536
    const size_t nX = (size_t)BB * LL * DD;   // 4,194,304

    u16* wf   = (u16*)d_ws;                   // Wq,Wk,Wv B-frag order (384 KB)
    u16* wo16 = wf + 3 * nW;                  // Wo K=16 A-frag order (128 KB)
    u16* qfr  = wf + 4 * nW;                  // 8 MB
    u16* kfr  = qfr + nX;                     // 8 MB
    u16* vfr  = kfr + nX;                     // 8 MB
    u16* part = vfr + nX;                     // 41.9 MB (4 x 80 x 128 KB)

    wconv_kernel<<<dim3(128), dim3(256), 0, stream>>>(Wq, Wk, Wv, Wo, wf, wo16);
    qkv_kernel<<<dim3(1024), dim3(256), 0, stream>>>(x, wf, qfr, kfr, vfr);
    attn_kernel<<<dim3(256), dim3(512), 0, stream>>>(qfr, kfr, vfr, part);
    oproj_kernel<<<dim3(1024), dim3(256), 0, stream>>>(part, wo16, out);
}